// Round 8
// baseline (183.030 us; speedup 1.0000x reference)
//
#include <hip/hip_runtime.h>
#include <hip/hip_bf16.h>

typedef unsigned long long u64;
typedef unsigned int u32;

#define A_TOTAL 76725
#define NCLS 90
#define KTOP 5000u
#define MAXT 100
#define KTHR 0x3D4CCCCDu         /* bits of 0.05f */
#define TCAP 2048u               /* per-lane candidate list capacity */

__device__ __forceinline__ u64 pack_key(u32 k, u32 i) {
  return ((u64)k << 32) | (u64)(0xFFFFFFFFu - i);
}

// Full wave-0 cut with totals: B = smallest bucket with count(>=B) >= need.
__device__ __forceinline__ void cut4096w(const u32* hh, u32 need, int wl,
                                         u32& B, u32& incl, u32& above, u32& total) {
  int lo = wl << 6;
  u32 s = 0;
  #pragma unroll
  for (int j = 0; j < 64; ++j) s += hh[lo + j];
  u32 suf = s;
  #pragma unroll
  for (int off = 1; off < 64; off <<= 1) {
    u32 v = __shfl_down(suf, off, 64);
    if (wl < 64 - off) suf += v;
  }
  total = __shfl(suf, 0, 64);
  if (total < need) { B = 0; incl = total; above = 0; return; }
  u32 sufnext = suf - s;
  bool cross = (suf >= need) && (sufnext < need);
  u64 bal = __ballot(cross);
  int gl = (int)__ffsll((unsigned long long)bal) - 1;
  int glo = gl << 6;
  u32 aboveG = __shfl(sufnext, gl, 64);
  u32 hb = hh[glo + wl];
  u32 sufb = hb;
  #pragma unroll
  for (int off = 1; off < 64; off <<= 1) {
    u32 v = __shfl_down(sufb, off, 64);
    if (wl < 64 - off) sufb += v;
  }
  bool c2 = (aboveG + sufb >= need) && (aboveG + sufb - hb < need);
  u64 bal2 = __ballot(c2);
  int jB = (int)__ffsll((unsigned long long)bal2) - 1;
  B = (u32)(glo + jB);
  incl = aboveG + __shfl(sufb, jB, 64);
  above = incl - __shfl(hb, jB, 64);
}

// Block-cooperative descending bitonic sort of a[0..n) padded to pow2 with 0.
__device__ __forceinline__ void bitonic_desc(u64* a, u32 n, int tid, int nth) {
  u32 P = 2; while (P < n) P <<= 1;
  for (u32 i = tid; i < P; i += nth) if (i >= n) a[i] = 0ULL;
  __syncthreads();
  for (u32 kk = 2; kk <= P; kk <<= 1) {
    for (u32 jj = kk >> 1; jj; jj >>= 1) {
      for (u32 i = tid; i < P; i += nth) {
        u32 ixj = i ^ jj;
        if (ixj > i) {
          u64 x = a[i], y = a[ixj];
          bool up = ((i & kk) == 0);
          if (up ? (x < y) : (x > y)) { a[i] = y; a[ixj] = x; }
        }
      }
      __syncthreads();
    }
  }
}

// Wave-level lazy greedy NMS scan over sorted candidates (one wave, no barriers).
__device__ __forceinline__ int lazy_scan(const u64* key_s, const float4* box_s, u32 C,
                                         float4* wbox, float* outS, float* outB,
                                         int w, int wl) {
  u32 cur = 0;
  while (w < MAXT && cur < C) {
    u32 p = cur + (u32)wl;
    bool aliveL = (p < C);
    u64 kk = aliveL ? key_s[p] : 0ull;
    float4 mybox;
    if (aliveL) mybox = box_s[p];
    float myarea = aliveL ? (mybox.z - mybox.x) * (mybox.w - mybox.y) : 0.f;
    for (int j = 0; j < w; ++j) {
      if (aliveL) {
        float4 pb = wbox[j];
        float yy1 = fmaxf(pb.x, mybox.x), xx1 = fmaxf(pb.y, mybox.y);
        float yy2 = fminf(pb.z, mybox.z), xx2 = fminf(pb.w, mybox.w);
        float inter = fmaxf(yy2 - yy1, 0.0f) * fmaxf(xx2 - xx1, 0.0f);
        float pa = (pb.z - pb.x) * (pb.w - pb.y);
        if (inter / (pa + myarea - inter + 1e-8f) > 0.3f) aliveL = false;
      }
    }
    for (;;) {
      u64 bal = __ballot(aliveL);
      if (bal == 0ull) break;
      int js = (int)__ffsll((unsigned long long)bal) - 1;
      float4 pb;
      pb.x = __shfl(mybox.x, js, 64);
      pb.y = __shfl(mybox.y, js, 64);
      pb.z = __shfl(mybox.z, js, 64);
      pb.w = __shfl(mybox.w, js, 64);
      u64 wk = __shfl(kk, js, 64);
      if (wl == 0) {
        outS[w] = __uint_as_float((u32)(wk >> 32));
        *(float4*)(outB + w * 4) = pb;
        wbox[w] = pb;
      }
      w++;
      if (w >= MAXT) break;
      if (wl <= js) aliveL = false;
      else if (aliveL) {
        float yy1 = fmaxf(pb.x, mybox.x), xx1 = fmaxf(pb.y, mybox.y);
        float yy2 = fminf(pb.z, mybox.z), xx2 = fminf(pb.w, mybox.w);
        float inter = fmaxf(yy2 - yy1, 0.0f) * fmaxf(xx2 - xx1, 0.0f);
        float pa = (pb.z - pb.x) * (pb.w - pb.y);
        if (inter / (pa + myarea - inter + 1e-8f) > 0.3f) aliveL = false;
      }
    }
    cur += 64;
  }
  return w;
}

// ---------------- decode + clip (+ zero counters/flags) ----------------
__global__ __launch_bounds__(256) void decode_kernel(
    const float* __restrict__ bx0, const float* __restrict__ bx1, const float* __restrict__ bx2,
    const float* __restrict__ bx3, const float* __restrict__ bx4,
    const float* __restrict__ an0, const float* __restrict__ an1, const float* __restrict__ an2,
    const float* __restrict__ an3, const float* __restrict__ an4,
    const float* __restrict__ img, float* __restrict__ boxes, u32* __restrict__ zero_base)
{
  int t = blockIdx.x * blockDim.x + threadIdx.x;
  int nth = gridDim.x * blockDim.x;
  for (int i = t; i < 180 * 64 + 360; i += nth) zero_base[i] = 0;   // cnt_pad + flags + C_g
  if (t >= 2 * A_TOTAL) return;
  int b = t / A_TOTAL, a = t % A_TOTAL;
  const float* bp; const float* ap; int al; int nl;
  if (a < 57600)      { bp = bx0; ap = an0; al = a;          nl = 57600; }
  else if (a < 72000) { bp = bx1; ap = an1; al = a - 57600;  nl = 14400; }
  else if (a < 75600) { bp = bx2; ap = an2; al = a - 72000;  nl = 3600;  }
  else if (a < 76500) { bp = bx3; ap = an3; al = a - 75600;  nl = 900;   }
  else                { bp = bx4; ap = an4; al = a - 76500;  nl = 225;   }
  float4 e  = *(const float4*)(bp + ((size_t)b * nl + al) * 4);
  float4 an = *(const float4*)(ap + ((size_t)b * nl + al) * 4);
  const float CLIP = 4.135166556742356f; // log(1000/16)
  float ah  = an.z - an.x + 1.0f;
  float aw  = an.w - an.y + 1.0f;
  float ayc = an.x + 0.5f * ah;
  float axc = an.y + 0.5f * aw;
  float dh = fminf(e.z, CLIP), dw = fminf(e.w, CLIP);
  float yc = e.x * ah + ayc;
  float xc = e.y * aw + axc;
  float h  = expf(dh) * ah;
  float w  = expf(dw) * aw;
  float ymin = yc - 0.5f * h;
  float xmin = xc - 0.5f * w;
  float ymax = ymin + h - 1.0f;
  float xmax = xmin + w - 1.0f;
  float H = img[b * 2 + 0], W = img[b * 2 + 1];
  float4 o;
  o.x = fminf(fmaxf(ymin, 0.0f), H);
  o.y = fminf(fmaxf(xmin, 0.0f), W);
  o.z = fminf(fmaxf(ymax, 0.0f), H);
  o.w = fminf(fmaxf(xmax, 0.0f), W);
  *(float4*)(boxes + (size_t)t * 4) = o;
}

// ---------------- direct candidate collect from raw class outputs (x>=0 <=> s>=0.5) ----------------
__global__ __launch_bounds__(256) void collect_kernel(
    const float* __restrict__ c3, const float* __restrict__ c4, const float* __restrict__ c5,
    const float* __restrict__ c6, const float* __restrict__ c7,
    u64* __restrict__ listT_g, u32* __restrict__ cnt_pad)
{
  __shared__ float lds[64 * 91];
  int blk = blockIdx.x;
  int lvl, local;
  if      (blk < 1800) { lvl = 0; local = blk; }
  else if (blk < 2250) { lvl = 1; local = blk - 1800; }
  else if (blk < 2364) { lvl = 2; local = blk - 2250; }
  else if (blk < 2394) { lvl = 3; local = blk - 2364; }
  else                 { lvl = 4; local = blk - 2394; }
  const int ns[5]    = {57600, 14400, 3600, 900, 225};
  const int bases[5] = {0, 57600, 72000, 75600, 76500};
  const int tl[5]    = {900, 225, 57, 15, 4};
  const float* cls = (lvl == 0) ? c3 : (lvl == 1) ? c4 : (lvl == 2) ? c5 : (lvl == 3) ? c6 : c7;
  int n = ns[lvl], base = bases[lvl], tiles = tl[lvl];
  int b = local / tiles, tile = local % tiles;
  int a0 = tile * 64;
  int cnt = n - a0; if (cnt > 64) cnt = 64;
  const float* src = cls + ((size_t)b * n + a0) * 91;
  int total = cnt * 91;
  for (int i = threadIdx.x; i < total; i += 256) lds[i] = src[i];
  __syncthreads();
  for (int j = threadIdx.x; j < NCLS * 64; j += 256) {
    int c = j >> 6, a = j & 63;
    if (a < cnt) {
      float x = lds[a * 91 + c + 1];
      if (x >= 0.0f) {                          // s >= 0.5
        float s = 1.0f / (1.0f + expf(-x));
        int lane = b * NCLS + c;
        u32 idx = (u32)(base + a0 + a);
        u32 p = atomicAdd(&cnt_pad[lane * 64], 1u);
        if (p < TCAP) listT_g[(size_t)lane * TCAP + p] = pack_key(__float_as_uint(s), idx);
      }
    }
  }
}

// ---------------- per-lane build: counting-sort candidates, gather boxes ----------------
__global__ __launch_bounds__(256) void build_kernel(
    const float* __restrict__ boxes, const u64* __restrict__ listT_g,
    const u32* __restrict__ cnt_pad, u32* __restrict__ C_g, u32* __restrict__ flags,
    u64* __restrict__ sortedK, float* __restrict__ sortedB)
{
  __shared__ u64 keyIn[2048];      // 16 KB
  __shared__ u32 histL[4096];      // 16 KB
  __shared__ u64 key_s[2048];      // 16 KB
  __shared__ u32 wtot[4];
  __shared__ u32 sh_big;
  int tid = threadIdx.x;
  int lane = blockIdx.x;
  int b = lane / NCLS;
  u32 cnt = cnt_pad[lane * 64];
  if (cnt > TCAP) { if (tid == 0) { flags[lane] = 1; C_g[lane] = 0; } return; }
  if (tid == 0) { C_g[lane] = cnt; sh_big = 0; }
  const u64* LT = listT_g + (size_t)lane * TCAP;
  for (u32 i = tid; i < cnt; i += 256) keyIn[i] = LT[i];
  for (int i = tid; i < 4096; i += 256) histL[i] = 0;
  __syncthreads();
  // histogram on affine digest over s in [0.5, 1.0] (monotone in s)
  for (u32 i = tid; i < cnt; i += 256) {
    float s = __uint_as_float((u32)(keyIn[i] >> 32));
    int d = (int)((s - 0.5f) * 8175.0f); d = min(max(d, 0), 4095);
    atomicAdd(&histL[d], 1u);
  }
  __syncthreads();
  // descending exclusive prefix (bucket 4095 first)
  {
    int t0 = tid << 4;
    u32 hloc[16]; u32 ssum = 0;
    #pragma unroll
    for (int j = 0; j < 16; ++j) { hloc[j] = histL[t0 + j]; ssum += hloc[j]; }
    int wl = tid & 63, wid = tid >> 6;
    u32 suf = ssum;
    #pragma unroll
    for (int off = 1; off < 64; off <<= 1) {
      u32 v = __shfl_down(suf, off, 64);
      if (wl < 64 - off) suf += v;
    }
    if (wl == 0) wtot[wid] = suf;
    __syncthreads();
    u32 cross = 0;
    for (int w2 = wid + 1; w2 < 4; ++w2) cross += wtot[w2];
    u32 run = (suf - ssum) + cross;
    #pragma unroll
    for (int j = 15; j >= 0; --j) { u32 b2 = run; run += hloc[j]; histL[t0 + j] = b2; }
  }
  __syncthreads();
  // scatter (histL becomes bucket ends)
  for (u32 i = tid; i < cnt; i += 256) {
    u64 k = keyIn[i];
    float s = __uint_as_float((u32)(k >> 32));
    int d = (int)((s - 0.5f) * 8175.0f); d = min(max(d, 0), 4095);
    u32 pos = atomicAdd(&histL[d], 1u);
    if (pos < TCAP) key_s[pos] = k;
  }
  __syncthreads();
  // per-bucket insertion minisort: bucket d spans [histL[d+1], histL[d])
  {
    int t0 = tid << 4;
    for (int j = 0; j < 16; ++j) {
      u32 d = (u32)(t0 + j);
      u32 end = histL[d];
      u32 start = (d == 4095u) ? 0u : histL[d + 1];
      u32 c = end - start;
      if (c >= 2u) {
        if (c <= 48u) {
          for (u32 a2 = start + 1; a2 < end; ++a2) {
            u64 kv = key_s[a2];
            int bi = (int)a2 - 1;
            while (bi >= (int)start && key_s[bi] < kv) { key_s[bi + 1] = key_s[bi]; --bi; }
            key_s[bi + 1] = kv;
          }
        } else sh_big = 1;
      }
    }
  }
  __syncthreads();
  if (sh_big) bitonic_desc(key_s, cnt, tid, 256);
  // write sorted keys + gathered boxes
  const float4* boxes4 = (const float4*)boxes;
  float4* sB = (float4*)sortedB;
  size_t obase = (size_t)lane * TCAP;
  size_t bbase = (size_t)b * A_TOTAL;
  for (u32 p = tid; p < cnt; p += 256) {
    u64 k = key_s[p];
    sortedK[obase + p] = k;
    u32 idx = 0xFFFFFFFFu - (u32)(k & 0xFFFFFFFFull);
    sB[obase + p] = boxes4[bbase + idx];
  }
}

// ---------------- per-lane scan: wave-synchronous lazy greedy NMS ----------------
__global__ __launch_bounds__(64) void scan_kernel(
    const u64* __restrict__ sortedK, const float* __restrict__ sortedB,
    const u32* __restrict__ C_g, u32* __restrict__ flags,
    float* __restrict__ nms_s, float* __restrict__ nms_b)
{
  __shared__ float4 wbox[MAXT];
  int lane = blockIdx.x;
  int wl = threadIdx.x;
  if (flags[lane]) return;
  int C = (int)C_g[lane];
  const u64* K = sortedK + (size_t)lane * TCAP;
  const float4* Bx = (const float4*)sortedB + (size_t)lane * TCAP;
  float* outS = nms_s + (size_t)lane * MAXT;
  float* outB = nms_b + (size_t)lane * MAXT * 4;
  int w = 0, cur = 0;
  while (w < MAXT && cur < C) {
    int p = cur + wl;
    bool alive = (p < C);
    u64 kk = alive ? K[p] : 0ull;
    float4 mybox;
    if (alive) mybox = Bx[p];
    float myarea = alive ? (mybox.z - mybox.x) * (mybox.w - mybox.y) : 0.f;
    for (int j = 0; j < w; ++j) {
      if (alive) {
        float4 pb = wbox[j];
        float yy1 = fmaxf(pb.x, mybox.x), xx1 = fmaxf(pb.y, mybox.y);
        float yy2 = fminf(pb.z, mybox.z), xx2 = fminf(pb.w, mybox.w);
        float inter = fmaxf(yy2 - yy1, 0.0f) * fmaxf(xx2 - xx1, 0.0f);
        float pa = (pb.z - pb.x) * (pb.w - pb.y);
        if (inter / (pa + myarea - inter + 1e-8f) > 0.3f) alive = false;
      }
    }
    for (;;) {
      u64 bal = __ballot(alive);
      if (bal == 0ull) break;
      int js = (int)__ffsll((unsigned long long)bal) - 1;
      float4 pb;
      pb.x = __shfl(mybox.x, js, 64);
      pb.y = __shfl(mybox.y, js, 64);
      pb.z = __shfl(mybox.z, js, 64);
      pb.w = __shfl(mybox.w, js, 64);
      u64 wk = __shfl(kk, js, 64);
      if (wl == 0) {
        outS[w] = __uint_as_float((u32)(wk >> 32));
        *(float4*)(outB + w * 4) = pb;
        wbox[w] = pb;
      }
      w++;
      if (w >= MAXT) break;
      if (wl <= js) alive = false;
      else if (alive) {
        float yy1 = fmaxf(pb.x, mybox.x), xx1 = fmaxf(pb.y, mybox.y);
        float yy2 = fminf(pb.z, mybox.z), xx2 = fminf(pb.w, mybox.w);
        float inter = fmaxf(yy2 - yy1, 0.0f) * fmaxf(xx2 - xx1, 0.0f);
        float pa = (pb.z - pb.x) * (pb.w - pb.y);
        if (inter / (pa + myarea - inter + 1e-8f) > 0.3f) alive = false;
      }
    }
    cur += 64;
  }
  // safety: must finish with 100 winners well inside the >=0.5 prefix
  if (w < MAXT || cur > C - 64) { if (wl == 0) flags[lane] = 1; return; }
}

// ---------------- exact fallback (rare): rebuild everything from raw column ----------------
__global__ __launch_bounds__(256) void fallback_kernel(
    const float* __restrict__ c3, const float* __restrict__ c4, const float* __restrict__ c5,
    const float* __restrict__ c6, const float* __restrict__ c7,
    const float* __restrict__ boxes, const u32* __restrict__ flags,
    float* __restrict__ nms_s, float* __restrict__ nms_b)
{
  __shared__ __align__(16) char big[40960];   // listA u64[5120] -> later {cntArr u32[4096] | box_s float4[2048]}
  __shared__ u64 listE[2048];
  __shared__ u64 key_s[2048];
  __shared__ u32 histL[4096];
  __shared__ float4 wbox[MAXT];
  __shared__ u32 wtot[4];
  __shared__ u64 sh_minPrev;
  __shared__ u32 sh_w, sh_done, sh_eidx, sh_Rthr, sh_eSorted, sh_big;
  __shared__ u32 sh_B, sh_incl, sh_above, sh_total, sh_cA, sh_cE, sh_B2;

  int lane = blockIdx.x;
  if (flags[lane] == 0) return;
  int tid = threadIdx.x;
  int b = lane / NCLS, c = lane % NCLS;
  const float4* boxes4 = (const float4*)boxes;
  size_t bbase = (size_t)b * A_TOTAL;
  const u64 thrpack = ((u64)KTHR) << 32;

  auto sb_of = [&](int i) -> u32 {
    const float* p; int al, nl;
    if (i < 57600)      { p = c3; al = i;          nl = 57600; }
    else if (i < 72000) { p = c4; al = i - 57600;  nl = 14400; }
    else if (i < 75600) { p = c5; al = i - 72000;  nl = 3600;  }
    else if (i < 76500) { p = c6; al = i - 75600;  nl = 900;   }
    else                { p = c7; al = i - 76500;  nl = 225;   }
    float x = p[((size_t)b * nl + al) * 91 + (c + 1)];
    float s = 1.0f / (1.0f + expf(-x));
    return __float_as_uint(s);
  };

  u64* listA = (u64*)big;
  // ---- pass 1: hist of s-bits >> 19 ----
  for (int i = tid; i < 4096; i += 256) histL[i] = 0;
  if (tid == 0) {
    sh_cA = 0; sh_cE = 0; sh_w = 0; sh_done = 0; sh_eidx = 0; sh_eSorted = 0; sh_minPrev = ~0ull;
  }
  __syncthreads();
  for (int i = tid; i < A_TOTAL; i += 256) atomicAdd(&histL[sb_of(i) >> 19], 1u);
  __syncthreads();
  if (tid < 64) {
    u32 Bx, ix, ax, tx;
    cut4096w(histL, KTOP, tid, Bx, ix, ax, tx);
    if (tid == 0) sh_B = Bx;
  }
  __syncthreads();
  u32 B = sh_B;
  // ---- pass 2: collect listA / listE ----
  for (int i = tid; i < A_TOTAL; i += 256) {
    u32 u = sb_of(i);
    u32 bkt = u >> 19;
    if (bkt > B) {
      u32 p = atomicAdd(&sh_cA, 1u);
      if (p < 5120u) listA[p] = pack_key(u, (u32)i);
    } else if (bkt == B) {
      u32 p = atomicAdd(&sh_cE, 1u);
      if (p < 2048u) listE[p] = pack_key(u, (u32)i);
    }
  }
  __syncthreads();
  u32 g = sh_cA, h = sh_cE;
  if (h > 2048u) {
    // refine boundary bucket on bits [18:7]
    for (int i = tid; i < 4096; i += 256) histL[i] = 0;
    if (tid == 0) sh_cE = 0;
    __syncthreads();
    for (int i = tid; i < A_TOTAL; i += 256) {
      u32 u = sb_of(i);
      if ((u >> 19) == B) atomicAdd(&histL[(u >> 7) & 0xFFFu], 1u);
    }
    __syncthreads();
    u32 R1 = KTOP - g;
    if (tid < 64) {
      u32 Bx, ix, ax, tx;
      cut4096w(histL, R1, tid, Bx, ix, ax, tx);
      if (tid == 0) sh_B2 = Bx;
    }
    __syncthreads();
    u32 B2 = sh_B2;
    for (int i = tid; i < A_TOTAL; i += 256) {
      u32 u = sb_of(i);
      if ((u >> 19) == B) {
        u32 sb2 = (u >> 7) & 0xFFFu;
        if (sb2 > B2) {
          u32 p = atomicAdd(&sh_cA, 1u);
          if (p < 5120u) listA[p] = pack_key(u, (u32)i);
        } else if (sb2 == B2) {
          u32 p = atomicAdd(&sh_cE, 1u);
          if (p < 2048u) listE[p] = pack_key(u, (u32)i);
        }
      }
    }
    __syncthreads();
    g = sh_cA; h = sh_cE; if (h > 2048u) h = 2048u;   // pathological tie clamp
  }
  if (g > 5120u) g = 5120u;
  u32 R = (g < KTOP) ? (KTOP - g) : 0u; if (R > h) R = h;

  // listA -> registers (threshold-filtered), then big[] is reused
  u64 ak[20];
  #pragma unroll
  for (int r = 0; r < 20; ++r) {
    u32 s2 = (u32)tid + (u32)r * 256u;
    u64 kp = (s2 < g) ? listA[s2] : 0ull;
    if (kp < thrpack) kp = 0ull;
    ak[r] = kp;
  }
  __syncthreads();
  float4* box_s = (float4*)big;
  u32* cntArr = (u32*)big;

  float* outS = nms_s + (size_t)lane * MAXT;
  float* outB = nms_b + (size_t)lane * MAXT * 4;
  const float LO0  = 0.04f;
  const float INV0 = 4096.0f / (1.001f - 0.04f);

  // ================= segment loop (exact; from proven R5-R7 machinery) =================
  for (int seg = 0; seg < 7200; ++seg) {
    __syncthreads();
    if (sh_w >= MAXT || sh_done) break;
    u64 minPrev = sh_minPrev;

    int digLvl = 0;
    u32 A_B0 = 0, A_B1 = 0;
    float lo1 = 0.f, inv1 = 0.f;
    u64 kMask = 0, kPref = 0;
    int m1shift = 32;
    int selMode = -1;
    u32 selB = 0;
    u32 C = 0;
    bool fromE = false;

    for (int lvl = 0; lvl < 8; ++lvl) {
      for (int i = tid; i < 4096; i += 256) histL[i] = 0;
      __syncthreads();
      #pragma unroll
      for (int r = 0; r < 20; ++r) {
        u64 k = ak[r];
        if (!k || k >= minPrev) continue;
        float s = __uint_as_float((u32)(k >> 32));
        if (digLvl >= 1) { int d0 = (int)((s - LO0) * INV0); d0 = min(max(d0, 0), 4095); if ((u32)d0 != A_B0) continue; }
        if (digLvl >= 2) { int d1 = (int)((s - lo1) * inv1); d1 = min(max(d1, 0), 4095); if ((u32)d1 != A_B1) continue; }
        if (digLvl >= 3 && ((k & kMask) != kPref)) continue;
        u32 d;
        if (digLvl == 0)      { int t0 = (int)((s - LO0) * INV0); d = (u32)min(max(t0, 0), 4095); }
        else if (digLvl == 1) { int t1 = (int)((s - lo1) * inv1); d = (u32)min(max(t1, 0), 4095); }
        else                  d = (u32)((k >> m1shift) & 0xFFFull);
        atomicAdd(&histL[d], 1u);
      }
      __syncthreads();
      if (tid < 64) {
        u32 Bx, ix, ax, tx;
        cut4096w(histL, 1024u, tid, Bx, ix, ax, tx);
        if (tid == 0) { sh_B = Bx; sh_incl = ix; sh_above = ax; sh_total = tx; }
      }
      __syncthreads();
      u32 total = sh_total, incl = sh_incl, above = sh_above, Bx = sh_B;
      if (total == 0u)   { fromE = true; break; }
      if (total < 1024u) { selMode = 0; C = total; break; }
      if (incl <= 2048u) { selMode = 1; selB = Bx; C = incl; break; }
      if (above > 0u)    { selMode = 2; selB = Bx; C = above; break; }
      if (digLvl == 0) {
        A_B0 = Bx;
        lo1 = LO0 + (float)Bx / INV0;
        inv1 = INV0 * 4096.0f;
        digLvl = 1;
      } else if (digLvl == 1) {
        A_B1 = Bx;
        digLvl = 2; m1shift = 32;
      } else {
        kPref |= ((u64)Bx << m1shift);
        kMask |= (0xFFFull << m1shift);
        m1shift -= 12;
        digLvl++;
      }
      __syncthreads();
    }

    if (fromE) {
      if (!sh_eSorted) {
        bitonic_desc(listE, h, tid, 256);
        if (tid == 0) {
          u32 lo = 0, hi2 = h;
          while (lo < hi2) { u32 mid = (lo + hi2) >> 1; if (listE[mid] >= thrpack) lo = mid + 1; else hi2 = mid; }
          sh_Rthr = (R < lo) ? R : lo;
          sh_eSorted = 1;
        }
        __syncthreads();
      }
      u32 eidx = sh_eidx;
      u32 take = (sh_Rthr > eidx) ? (sh_Rthr - eidx) : 0u;
      if (take > 2048u) take = 2048u;
      if (take == 0u) { if (tid == 0) sh_done = 1; continue; }
      for (u32 i = tid; i < take; i += 256) key_s[i] = listE[eidx + i];
      C = take;
      if (tid == 0) sh_eidx = eidx + take;
    } else {
      // descending exclusive prefix over histL
      u32 hloc[16];
      {
        int t0 = tid << 4;
        u32 ssum = 0;
        #pragma unroll
        for (int j = 0; j < 16; ++j) { hloc[j] = histL[t0 + j]; ssum += hloc[j]; }
        int wl = tid & 63, wid = tid >> 6;
        u32 suf = ssum;
        #pragma unroll
        for (int off = 1; off < 64; off <<= 1) {
          u32 v = __shfl_down(suf, off, 64);
          if (wl < 64 - off) suf += v;
        }
        if (wl == 0) wtot[wid] = suf;
        __syncthreads();
        u32 cross = 0;
        for (int w2 = wid + 1; w2 < 4; ++w2) cross += wtot[w2];
        u32 run = (suf - ssum) + cross;
        #pragma unroll
        for (int j = 15; j >= 0; --j) { u32 base2 = run; run += hloc[j]; histL[t0 + j] = base2; }
      }
      for (int i = tid; i < 4096; i += 256) cntArr[i] = 0;
      if (tid == 0) sh_big = 0;
      __syncthreads();
      #pragma unroll
      for (int r = 0; r < 20; ++r) {
        u64 k = ak[r];
        if (!k || k >= minPrev) continue;
        float s = __uint_as_float((u32)(k >> 32));
        if (digLvl >= 1) { int d0 = (int)((s - LO0) * INV0); d0 = min(max(d0, 0), 4095); if ((u32)d0 != A_B0) continue; }
        if (digLvl >= 2) { int d1 = (int)((s - lo1) * inv1); d1 = min(max(d1, 0), 4095); if ((u32)d1 != A_B1) continue; }
        if (digLvl >= 3 && ((k & kMask) != kPref)) continue;
        u32 d;
        if (digLvl == 0)      { int t0x = (int)((s - LO0) * INV0); d = (u32)min(max(t0x, 0), 4095); }
        else if (digLvl == 1) { int t1x = (int)((s - lo1) * inv1); d = (u32)min(max(t1x, 0), 4095); }
        else                  d = (u32)((k >> m1shift) & 0xFFFull);
        if (selMode == 1)      { if (d < selB) continue; }
        else if (selMode == 2) { if (d <= selB) continue; }
        u32 pos = histL[d] + atomicAdd(&cntArr[d], 1u);
        if (pos < 2048u) key_s[pos] = k;
      }
      __syncthreads();
      {
        int t0 = tid << 4;
        for (int j = 0; j < 16; ++j) {
          u32 bkt = (u32)(t0 + j);
          u32 cc = cntArr[bkt];
          if (cc >= 2u) {
            if (cc <= 48u) {
              u32 basep = histL[bkt];
              for (u32 a2 = 1; a2 < cc; ++a2) {
                u64 kv = key_s[basep + a2];
                int bi = (int)a2 - 1;
                while (bi >= 0 && key_s[basep + bi] < kv) { key_s[basep + bi + 1] = key_s[basep + bi]; --bi; }
                key_s[basep + bi + 1] = kv;
              }
            } else sh_big = 1;
          }
        }
      }
      __syncthreads();
      if (sh_big) bitonic_desc(key_s, C, tid, 256);
      if (tid == 0) sh_minPrev = key_s[C - 1];
    }
    __syncthreads();

    for (u32 p = tid; p < C; p += 256) {
      u32 idx = 0xFFFFFFFFu - (u32)(key_s[p] & 0xFFFFFFFFull);
      box_s[p] = boxes4[bbase + idx];
    }
    __syncthreads();

    if (tid < 64) {
      int w = lazy_scan(key_s, box_s, C, wbox, outS, outB, (int)sh_w, tid);
      if (tid == 0) sh_w = (u32)w;
    }
  }

  __syncthreads();
  u32 w = sh_w;
  for (u32 p = w + (u32)tid; p < MAXT; p += 256) {
    outS[p] = -1.0f;
    *(float4*)(outB + p * 4) = make_float4(0.f, 0.f, 0.f, 0.f);
  }
}

// ---------------- final per-batch top-100: radix rank-select ----------------
__global__ __launch_bounds__(256) void merge_kernel(
    const float* __restrict__ nms_s, const float* __restrict__ nms_b,
    float* __restrict__ out_b, float* __restrict__ out_s,
    float* __restrict__ out_c, float* __restrict__ out_v)
{
  __shared__ u64 keys[NCLS * MAXT];   // 72 KB
  __shared__ u32 hist[4096];          // 16 KB
  __shared__ u64 sel[640];
  __shared__ u32 sh_cnt, sh_valid;
  __shared__ u32 sh_B, sh_incl, sh_above, sh_total;

  int b = blockIdx.x, tid = threadIdx.x;
  const int NTOT = NCLS * MAXT;

  for (int i = tid; i < NTOT; i += 256) {
    float s = nms_s[(size_t)b * NTOT + i];
    u32 u = __float_as_uint(s);
    u = (u & 0x80000000u) ? ~u : (u | 0x80000000u);
    keys[i] = ((u64)u << 32) | (u64)(0xFFFFFFFFu - (u32)i);
  }
  if (tid == 0) { sh_cnt = 0; sh_valid = 0; }

  u64 prefVal = 0;
  u64 T = 0;
  u32 need = MAXT;
  const int shifts[6] = {52, 40, 28, 16, 4, 0};
  const int widths[6] = {12, 12, 12, 12, 12, 4};
  for (int lvl = 0; lvl < 6; ++lvl) {
    int s = shifts[lvl], w = widths[lvl];
    for (int i = tid; i < 4096; i += 256) hist[i] = 0;
    __syncthreads();
    u32 dmask = (1u << w) - 1u;
    for (int i = tid; i < NTOT; i += 256) {
      u64 k = keys[i];
      if (lvl > 0 && (k >> (s + w)) != (prefVal >> (s + w))) continue;
      atomicAdd(&hist[(u32)((k >> s) & dmask)], 1u);
    }
    __syncthreads();
    if (tid < 64) {
      u32 Bx, ix, ax, tx;
      cut4096w(hist, need, tid, Bx, ix, ax, tx);
      if (tid == 0) { sh_B = Bx; sh_incl = ix; sh_above = ax; sh_total = tx; }
    }
    __syncthreads();
    u32 B = sh_B, incl = sh_incl, above = sh_above;
    if (incl <= 512u || lvl == 5) {
      T = prefVal | ((u64)B << s);
      break;
    }
    prefVal |= ((u64)B << s);
    need -= above;
  }
  __syncthreads();

  for (int i = tid; i < NTOT; i += 256) {
    u64 k = keys[i];
    if (k >= T) {
      u32 p = atomicAdd(&sh_cnt, 1u);
      if (p < 640u) sel[p] = k;
    }
  }
  __syncthreads();
  u32 cnt = sh_cnt; if (cnt > 640u) cnt = 640u;

  for (u32 j = tid; j < cnt; j += 256) {
    u64 kj = sel[j];
    u32 r = 0;
    for (u32 i = 0; i < cnt; ++i) r += (sel[i] > kj) ? 1u : 0u;
    if (r < (u32)MAXT) {
      u32 u = (u32)(kj >> 32);
      u32 bits = (u & 0x80000000u) ? (u ^ 0x80000000u) : ~u;
      float sc = __uint_as_float(bits);
      u32 flat = 0xFFFFFFFFu - (u32)(kj & 0xFFFFFFFFull);
      int cls = (int)(flat / MAXT), pos = (int)(flat % MAXT);
      out_s[b * MAXT + r] = sc;
      out_c[b * MAXT + r] = (float)(cls + 1);
      *(float4*)(out_b + ((size_t)b * MAXT + r) * 4) =
          *(const float4*)(nms_b + (((size_t)b * NCLS + cls) * MAXT + pos) * 4);
      if (sc > -1.0f) atomicAdd(&sh_valid, 1u);
    }
  }
  __syncthreads();
  if (tid == 0) out_v[b] = (float)sh_valid;
}

extern "C" void kernel_launch(void* const* d_in, const int* in_sizes, int n_in,
                              void* d_out, int out_size, void* d_ws, size_t ws_size,
                              hipStream_t stream)
{
  const float* box[5]; const float* cls[5]; const float* anc[5];
  bool interleaved = (in_sizes[1] == 2 * 57600 * 91);   // setup_inputs dict order
  if (interleaved) {
    for (int l = 0; l < 5; ++l) {
      box[l] = (const float*)d_in[3 * l + 0];
      cls[l] = (const float*)d_in[3 * l + 1];
      anc[l] = (const float*)d_in[3 * l + 2];
    }
  } else {
    for (int l = 0; l < 5; ++l) {
      box[l] = (const float*)d_in[l];
      cls[l] = (const float*)d_in[5 + l];
      anc[l] = (const float*)d_in[10 + l];
    }
  }
  const float* img = (const float*)d_in[15];

  float* ws = (float*)d_ws;
  float* boxes_ws = ws;                              // 613800 f
  u32*   cnt_pad  = (u32*)(boxes_ws + 613800);       // 180*64 u32 (256B-strided counters)
  u32*   flags    = cnt_pad + 180 * 64;              // 180 u32
  u32*   C_g      = flags + 180;                     // 180 u32
  u64*   listT_g  = (u64*)(C_g + 180);               // 180*2048 u64
  u64*   sortedK  = listT_g + 180 * 2048;            // 180*2048 u64
  float* sortedB  = (float*)(sortedK + 180 * 2048);  // 180*2048*4 f
  float* nms_s    = sortedB + 180 * 2048 * 4;        // 18000 f
  float* nms_b    = nms_s + 18000;                   // 72000 f

  decode_kernel<<<600, 256, 0, stream>>>(
      box[0], box[1], box[2], box[3], box[4],
      anc[0], anc[1], anc[2], anc[3], anc[4], img, boxes_ws, cnt_pad);

  collect_kernel<<<2402, 256, 0, stream>>>(cls[0], cls[1], cls[2], cls[3], cls[4],
                                           listT_g, cnt_pad);

  build_kernel<<<180, 256, 0, stream>>>(boxes_ws, listT_g, cnt_pad, C_g, flags,
                                        sortedK, sortedB);

  scan_kernel<<<180, 64, 0, stream>>>(sortedK, sortedB, C_g, flags, nms_s, nms_b);

  fallback_kernel<<<180, 256, 0, stream>>>(cls[0], cls[1], cls[2], cls[3], cls[4],
                                           boxes_ws, flags, nms_s, nms_b);

  float* out_b = (float*)d_out;  // [2][100][4]
  float* out_s = out_b + 800;    // [2][100]
  float* out_c = out_s + 200;    // [2][100]
  float* out_v = out_c + 200;    // [2]
  merge_kernel<<<2, 256, 0, stream>>>(nms_s, nms_b, out_b, out_s, out_c, out_v);
}

// Round 9
// 132.433 us; speedup vs baseline: 1.3821x; 1.3821x over previous
//
#include <hip/hip_runtime.h>
#include <hip/hip_bf16.h>

typedef unsigned long long u64;
typedef unsigned int u32;

#define A_TOTAL 76725
#define NCLS 90
#define KTOP 5000u
#define MAXT 100
#define KTHR 0x3D4CCCCDu         /* bits of 0.05f */
#define TCAP 2048u               /* per-lane candidate list capacity */

__device__ __forceinline__ u64 pack_key(u32 k, u32 i) {
  return ((u64)k << 32) | (u64)(0xFFFFFFFFu - i);
}

// Full wave-0 cut with totals: B = smallest bucket with count(>=B) >= need.
__device__ __forceinline__ void cut4096w(const u32* hh, u32 need, int wl,
                                         u32& B, u32& incl, u32& above, u32& total) {
  int lo = wl << 6;
  u32 s = 0;
  #pragma unroll
  for (int j = 0; j < 64; ++j) s += hh[lo + j];
  u32 suf = s;
  #pragma unroll
  for (int off = 1; off < 64; off <<= 1) {
    u32 v = __shfl_down(suf, off, 64);
    if (wl < 64 - off) suf += v;
  }
  total = __shfl(suf, 0, 64);
  if (total < need) { B = 0; incl = total; above = 0; return; }
  u32 sufnext = suf - s;
  bool cross = (suf >= need) && (sufnext < need);
  u64 bal = __ballot(cross);
  int gl = (int)__ffsll((unsigned long long)bal) - 1;
  int glo = gl << 6;
  u32 aboveG = __shfl(sufnext, gl, 64);
  u32 hb = hh[glo + wl];
  u32 sufb = hb;
  #pragma unroll
  for (int off = 1; off < 64; off <<= 1) {
    u32 v = __shfl_down(sufb, off, 64);
    if (wl < 64 - off) sufb += v;
  }
  bool c2 = (aboveG + sufb >= need) && (aboveG + sufb - hb < need);
  u64 bal2 = __ballot(c2);
  int jB = (int)__ffsll((unsigned long long)bal2) - 1;
  B = (u32)(glo + jB);
  incl = aboveG + __shfl(sufb, jB, 64);
  above = incl - __shfl(hb, jB, 64);
}

// Block-cooperative descending bitonic sort of a[0..n) padded to pow2 with 0.
__device__ __forceinline__ void bitonic_desc(u64* a, u32 n, int tid, int nth) {
  u32 P = 2; while (P < n) P <<= 1;
  for (u32 i = tid; i < P; i += nth) if (i >= n) a[i] = 0ULL;
  __syncthreads();
  for (u32 kk = 2; kk <= P; kk <<= 1) {
    for (u32 jj = kk >> 1; jj; jj >>= 1) {
      for (u32 i = tid; i < P; i += nth) {
        u32 ixj = i ^ jj;
        if (ixj > i) {
          u64 x = a[i], y = a[ixj];
          bool up = ((i & kk) == 0);
          if (up ? (x < y) : (x > y)) { a[i] = y; a[ixj] = x; }
        }
      }
      __syncthreads();
    }
  }
}

// Wave-level lazy greedy NMS scan over sorted candidates (one wave, no barriers).
__device__ __forceinline__ int lazy_scan(const u64* key_s, const float4* box_s, u32 C,
                                         float4* wbox, float* outS, float* outB,
                                         int w, int wl) {
  u32 cur = 0;
  while (w < MAXT && cur < C) {
    u32 p = cur + (u32)wl;
    bool aliveL = (p < C);
    u64 kk = aliveL ? key_s[p] : 0ull;
    float4 mybox;
    if (aliveL) mybox = box_s[p];
    float myarea = aliveL ? (mybox.z - mybox.x) * (mybox.w - mybox.y) : 0.f;
    for (int j = 0; j < w; ++j) {
      if (aliveL) {
        float4 pb = wbox[j];
        float yy1 = fmaxf(pb.x, mybox.x), xx1 = fmaxf(pb.y, mybox.y);
        float yy2 = fminf(pb.z, mybox.z), xx2 = fminf(pb.w, mybox.w);
        float inter = fmaxf(yy2 - yy1, 0.0f) * fmaxf(xx2 - xx1, 0.0f);
        float pa = (pb.z - pb.x) * (pb.w - pb.y);
        if (inter / (pa + myarea - inter + 1e-8f) > 0.3f) aliveL = false;
      }
    }
    for (;;) {
      u64 bal = __ballot(aliveL);
      if (bal == 0ull) break;
      int js = (int)__ffsll((unsigned long long)bal) - 1;
      float4 pb;
      pb.x = __shfl(mybox.x, js, 64);
      pb.y = __shfl(mybox.y, js, 64);
      pb.z = __shfl(mybox.z, js, 64);
      pb.w = __shfl(mybox.w, js, 64);
      u64 wk = __shfl(kk, js, 64);
      if (wl == 0) {
        outS[w] = __uint_as_float((u32)(wk >> 32));
        *(float4*)(outB + w * 4) = pb;
        wbox[w] = pb;
      }
      w++;
      if (w >= MAXT) break;
      if (wl <= js) aliveL = false;
      else if (aliveL) {
        float yy1 = fmaxf(pb.x, mybox.x), xx1 = fmaxf(pb.y, mybox.y);
        float yy2 = fminf(pb.z, mybox.z), xx2 = fminf(pb.w, mybox.w);
        float inter = fmaxf(yy2 - yy1, 0.0f) * fmaxf(xx2 - xx1, 0.0f);
        float pa = (pb.z - pb.x) * (pb.w - pb.y);
        if (inter / (pa + myarea - inter + 1e-8f) > 0.3f) aliveL = false;
      }
    }
    cur += 64;
  }
  return w;
}

// ---------------- decode + clip (+ zero counters) ----------------
__global__ __launch_bounds__(256) void decode_kernel(
    const float* __restrict__ bx0, const float* __restrict__ bx1, const float* __restrict__ bx2,
    const float* __restrict__ bx3, const float* __restrict__ bx4,
    const float* __restrict__ an0, const float* __restrict__ an1, const float* __restrict__ an2,
    const float* __restrict__ an3, const float* __restrict__ an4,
    const float* __restrict__ img, float* __restrict__ boxes, u32* __restrict__ zero_base)
{
  int t = blockIdx.x * blockDim.x + threadIdx.x;
  int nth = gridDim.x * blockDim.x;
  for (int i = t; i < 180 * 64; i += nth) zero_base[i] = 0;   // cnt_pad
  if (t >= 2 * A_TOTAL) return;
  int b = t / A_TOTAL, a = t % A_TOTAL;
  const float* bp; const float* ap; int al; int nl;
  if (a < 57600)      { bp = bx0; ap = an0; al = a;          nl = 57600; }
  else if (a < 72000) { bp = bx1; ap = an1; al = a - 57600;  nl = 14400; }
  else if (a < 75600) { bp = bx2; ap = an2; al = a - 72000;  nl = 3600;  }
  else if (a < 76500) { bp = bx3; ap = an3; al = a - 75600;  nl = 900;   }
  else                { bp = bx4; ap = an4; al = a - 76500;  nl = 225;   }
  float4 e  = *(const float4*)(bp + ((size_t)b * nl + al) * 4);
  float4 an = *(const float4*)(ap + ((size_t)b * nl + al) * 4);
  const float CLIP = 4.135166556742356f; // log(1000/16)
  float ah  = an.z - an.x + 1.0f;
  float aw  = an.w - an.y + 1.0f;
  float ayc = an.x + 0.5f * ah;
  float axc = an.y + 0.5f * aw;
  float dh = fminf(e.z, CLIP), dw = fminf(e.w, CLIP);
  float yc = e.x * ah + ayc;
  float xc = e.y * aw + axc;
  float h  = expf(dh) * ah;
  float w  = expf(dw) * aw;
  float ymin = yc - 0.5f * h;
  float xmin = xc - 0.5f * w;
  float ymax = ymin + h - 1.0f;
  float xmax = xmin + w - 1.0f;
  float H = img[b * 2 + 0], W = img[b * 2 + 1];
  float4 o;
  o.x = fminf(fmaxf(ymin, 0.0f), H);
  o.y = fminf(fmaxf(xmin, 0.0f), W);
  o.z = fminf(fmaxf(ymax, 0.0f), H);
  o.w = fminf(fmaxf(xmax, 0.0f), W);
  *(float4*)(boxes + (size_t)t * 4) = o;
}

// ---------------- streaming candidate collect (x>=0 <=> s>=0.5), no LDS ----------------
__device__ __forceinline__ void coll_elem(int i, float x, int b, int base,
                                          u64* __restrict__ listT_g, u32* __restrict__ cnt_pad) {
  if (x >= 0.0f) {
    u32 a = (u32)i / 91u;            // compile-time magic-mul
    u32 c = (u32)i - a * 91u;
    if (c != 0u) {
      float s = 1.0f / (1.0f + expf(-x));
      int lane = b * NCLS + (int)c - 1;
      u32 idx = (u32)base + a;
      u32 p = atomicAdd(&cnt_pad[lane * 64], 1u);
      if (p < TCAP) listT_g[(size_t)lane * TCAP + p] = pack_key(__float_as_uint(s), idx);
    }
  }
}

__global__ __launch_bounds__(256) void collect_kernel(
    const float* __restrict__ c3, const float* __restrict__ c4, const float* __restrict__ c5,
    const float* __restrict__ c6, const float* __restrict__ c7,
    u64* __restrict__ listT_g, u32* __restrict__ cnt_pad)
{
  int blk = blockIdx.x, tid = threadIdx.x;
  const float* cls; int n, base, b, loc, J, lvl;
  if (blk < 1280)      { lvl = 0; cls = c3; n = 57600; base = 0;     J = 640; int r = blk;        b = r >= J; loc = b ? r - J : r; }
  else if (blk < 1600) { lvl = 1; cls = c4; n = 14400; base = 57600; J = 160; int r = blk - 1280; b = r >= J; loc = b ? r - J : r; }
  else if (blk < 1680) { lvl = 2; cls = c5; n = 3600;  base = 72000; J = 40;  int r = blk - 1600; b = r >= J; loc = b ? r - J : r; }
  else if (blk < 1700) { lvl = 3; cls = c6; n = 900;   base = 75600; J = 10;  int r = blk - 1680; b = r >= J; loc = b ? r - J : r; }
  else                 { lvl = 4; cls = c7; n = 225;   base = 76500; J = 5;   int r = blk - 1700; b = r >= J; loc = b ? r - J : r; }

  if (lvl <= 3) {
    int F4 = n * 91 / 4;
    int chunk = (F4 + J - 1) / J;
    int q0 = loc * chunk;
    int q1 = q0 + chunk; if (q1 > F4) q1 = F4;
    const float4* src4 = (const float4*)(cls + (size_t)b * n * 91);
    for (int q = q0 + tid; q < q1; q += 256) {
      float4 v = src4[q];
      int i0 = q << 2;
      coll_elem(i0,     v.x, b, base, listT_g, cnt_pad);
      coll_elem(i0 + 1, v.y, b, base, listT_g, cnt_pad);
      coll_elem(i0 + 2, v.z, b, base, listT_g, cnt_pad);
      coll_elem(i0 + 3, v.w, b, base, listT_g, cnt_pad);
    }
  } else {
    int F = n * 91;                  // 20475 (not /4-divisible) -> scalar
    int chunk = (F + J - 1) / J;
    int s0 = loc * chunk;
    int s1 = s0 + chunk; if (s1 > F) s1 = F;
    const float* src = cls + (size_t)b * F;
    for (int i = s0 + tid; i < s1; i += 256) coll_elem(i, src[i], b, base, listT_g, cnt_pad);
  }
}

// ---------------- fused per-lane NMS: build + scan + exact in-kernel fallback ----------------
__global__ __launch_bounds__(256) void nms_kernel(
    const float* __restrict__ c3, const float* __restrict__ c4, const float* __restrict__ c5,
    const float* __restrict__ c6, const float* __restrict__ c7,
    const float* __restrict__ boxes, const u64* __restrict__ listT_g,
    const u32* __restrict__ cnt_pad, float* __restrict__ nms_s, float* __restrict__ nms_b)
{
  __shared__ __align__(16) char big[40960];   // fast: box_s float4[2048]; fallback: listA u64[5120] -> {cntArr|box_s}
  __shared__ __align__(16) u64 ebuf[2048];    // fast: keyIn; fallback: listE
  __shared__ u64 key_s[2048];
  __shared__ u32 histL[4096];
  __shared__ float4 wbox[MAXT];
  __shared__ u32 wtot[4];
  __shared__ u32 sh_flag, sh_bigS;
  __shared__ u64 sh_minPrev;
  __shared__ u32 sh_w, sh_done, sh_eidx, sh_Rthr, sh_eSorted, sh_bigF;
  __shared__ u32 sh_B, sh_incl, sh_above, sh_total, sh_cA, sh_cE, sh_B2;

  int tid = threadIdx.x;
  int lane = blockIdx.x;
  int b = lane / NCLS, c = lane % NCLS;
  const float4* boxes4 = (const float4*)boxes;
  size_t bbase = (size_t)b * A_TOTAL;
  const u64 thrpack = ((u64)KTHR) << 32;

  float* outS = nms_s + (size_t)lane * MAXT;
  float* outB = nms_b + (size_t)lane * MAXT * 4;

  u32 cnt = cnt_pad[lane * 64];
  if (tid == 0) { sh_flag = (cnt > TCAP) ? 1u : 0u; sh_bigS = 0; }
  __syncthreads();

  // ================= FAST PATH =================
  if (!sh_flag) {
    u64* keyIn = ebuf;
    float4* box_s = (float4*)big;
    const u64* LT = listT_g + (size_t)lane * TCAP;
    for (u32 i = tid; i < cnt; i += 256) keyIn[i] = LT[i];
    for (int i = tid; i < 4096; i += 256) histL[i] = 0;
    __syncthreads();
    for (u32 i = tid; i < cnt; i += 256) {
      float s = __uint_as_float((u32)(keyIn[i] >> 32));
      int d = (int)((s - 0.5f) * 8175.0f); d = min(max(d, 0), 4095);
      atomicAdd(&histL[d], 1u);
    }
    __syncthreads();
    {
      int t0 = tid << 4;
      u32 hloc[16]; u32 ssum = 0;
      #pragma unroll
      for (int j = 0; j < 16; ++j) { hloc[j] = histL[t0 + j]; ssum += hloc[j]; }
      int wl = tid & 63, wid = tid >> 6;
      u32 suf = ssum;
      #pragma unroll
      for (int off = 1; off < 64; off <<= 1) {
        u32 v = __shfl_down(suf, off, 64);
        if (wl < 64 - off) suf += v;
      }
      if (wl == 0) wtot[wid] = suf;
      __syncthreads();
      u32 cross = 0;
      for (int w2 = wid + 1; w2 < 4; ++w2) cross += wtot[w2];
      u32 run = (suf - ssum) + cross;
      #pragma unroll
      for (int j = 15; j >= 0; --j) { u32 b2 = run; run += hloc[j]; histL[t0 + j] = b2; }
    }
    __syncthreads();
    for (u32 i = tid; i < cnt; i += 256) {
      u64 k = keyIn[i];
      float s = __uint_as_float((u32)(k >> 32));
      int d = (int)((s - 0.5f) * 8175.0f); d = min(max(d, 0), 4095);
      u32 pos = atomicAdd(&histL[d], 1u);
      if (pos < TCAP) key_s[pos] = k;
    }
    __syncthreads();
    {
      int t0 = tid << 4;
      for (int j = 0; j < 16; ++j) {
        u32 d = (u32)(t0 + j);
        u32 end = histL[d];
        u32 start = (d == 4095u) ? 0u : histL[d + 1];
        u32 cc = end - start;
        if (cc >= 2u) {
          if (cc <= 48u) {
            for (u32 a2 = start + 1; a2 < end; ++a2) {
              u64 kv = key_s[a2];
              int bi = (int)a2 - 1;
              while (bi >= (int)start && key_s[bi] < kv) { key_s[bi + 1] = key_s[bi]; --bi; }
              key_s[bi + 1] = kv;
            }
          } else sh_bigS = 1;
        }
      }
    }
    __syncthreads();
    if (sh_bigS) bitonic_desc(key_s, cnt, tid, 256);
    for (u32 p = tid; p < cnt; p += 256) {
      u32 idx = 0xFFFFFFFFu - (u32)(key_s[p] & 0xFFFFFFFFull);
      box_s[p] = boxes4[bbase + idx];
    }
    __syncthreads();
    if (tid < 64) {
      int wl = tid;
      int C = (int)cnt;
      int w = 0, cur = 0;
      while (w < MAXT && cur < C) {
        int p = cur + wl;
        bool alive = (p < C);
        u64 kk = alive ? key_s[p] : 0ull;
        float4 mybox;
        if (alive) mybox = box_s[p];
        float myarea = alive ? (mybox.z - mybox.x) * (mybox.w - mybox.y) : 0.f;
        for (int j = 0; j < w; ++j) {
          if (alive) {
            float4 pb = wbox[j];
            float yy1 = fmaxf(pb.x, mybox.x), xx1 = fmaxf(pb.y, mybox.y);
            float yy2 = fminf(pb.z, mybox.z), xx2 = fminf(pb.w, mybox.w);
            float inter = fmaxf(yy2 - yy1, 0.0f) * fmaxf(xx2 - xx1, 0.0f);
            float pa = (pb.z - pb.x) * (pb.w - pb.y);
            if (inter / (pa + myarea - inter + 1e-8f) > 0.3f) alive = false;
          }
        }
        for (;;) {
          u64 bal = __ballot(alive);
          if (bal == 0ull) break;
          int js = (int)__ffsll((unsigned long long)bal) - 1;
          float4 pb;
          pb.x = __shfl(mybox.x, js, 64);
          pb.y = __shfl(mybox.y, js, 64);
          pb.z = __shfl(mybox.z, js, 64);
          pb.w = __shfl(mybox.w, js, 64);
          u64 wk = __shfl(kk, js, 64);
          if (wl == 0) {
            outS[w] = __uint_as_float((u32)(wk >> 32));
            *(float4*)(outB + w * 4) = pb;
            wbox[w] = pb;
          }
          w++;
          if (w >= MAXT) break;
          if (wl <= js) alive = false;
          else if (alive) {
            float yy1 = fmaxf(pb.x, mybox.x), xx1 = fmaxf(pb.y, mybox.y);
            float yy2 = fminf(pb.z, mybox.z), xx2 = fminf(pb.w, mybox.w);
            float inter = fmaxf(yy2 - yy1, 0.0f) * fmaxf(xx2 - xx1, 0.0f);
            float pa = (pb.z - pb.x) * (pb.w - pb.y);
            if (inter / (pa + myarea - inter + 1e-8f) > 0.3f) alive = false;
          }
        }
        cur += 64;
      }
      if (wl == 0 && (w < MAXT || cur > C - 64)) sh_flag = 1;
    }
  }
  __syncthreads();
  if (!sh_flag) return;

  // ================= EXACT FALLBACK (rare) =================
  auto sb_of = [&](int i) -> u32 {
    const float* p; int al, nl;
    if (i < 57600)      { p = c3; al = i;          nl = 57600; }
    else if (i < 72000) { p = c4; al = i - 57600;  nl = 14400; }
    else if (i < 75600) { p = c5; al = i - 72000;  nl = 3600;  }
    else if (i < 76500) { p = c6; al = i - 75600;  nl = 900;   }
    else                { p = c7; al = i - 76500;  nl = 225;   }
    float x = p[((size_t)b * nl + al) * 91 + (c + 1)];
    float s = 1.0f / (1.0f + expf(-x));
    return __float_as_uint(s);
  };

  u64* listA = (u64*)big;
  u64* listE = ebuf;
  for (int i = tid; i < 4096; i += 256) histL[i] = 0;
  if (tid == 0) {
    sh_cA = 0; sh_cE = 0; sh_w = 0; sh_done = 0; sh_eidx = 0; sh_eSorted = 0; sh_minPrev = ~0ull;
  }
  __syncthreads();
  for (int i = tid; i < A_TOTAL; i += 256) atomicAdd(&histL[sb_of(i) >> 19], 1u);
  __syncthreads();
  if (tid < 64) {
    u32 Bx, ix, ax, tx;
    cut4096w(histL, KTOP, tid, Bx, ix, ax, tx);
    if (tid == 0) sh_B = Bx;
  }
  __syncthreads();
  u32 B = sh_B;
  for (int i = tid; i < A_TOTAL; i += 256) {
    u32 u = sb_of(i);
    u32 bkt = u >> 19;
    if (bkt > B) {
      u32 p = atomicAdd(&sh_cA, 1u);
      if (p < 5120u) listA[p] = pack_key(u, (u32)i);
    } else if (bkt == B) {
      u32 p = atomicAdd(&sh_cE, 1u);
      if (p < 2048u) listE[p] = pack_key(u, (u32)i);
    }
  }
  __syncthreads();
  u32 g = sh_cA, h = sh_cE;
  if (h > 2048u) {
    for (int i = tid; i < 4096; i += 256) histL[i] = 0;
    if (tid == 0) sh_cE = 0;
    __syncthreads();
    for (int i = tid; i < A_TOTAL; i += 256) {
      u32 u = sb_of(i);
      if ((u >> 19) == B) atomicAdd(&histL[(u >> 7) & 0xFFFu], 1u);
    }
    __syncthreads();
    u32 R1 = KTOP - g;
    if (tid < 64) {
      u32 Bx, ix, ax, tx;
      cut4096w(histL, R1, tid, Bx, ix, ax, tx);
      if (tid == 0) sh_B2 = Bx;
    }
    __syncthreads();
    u32 B2 = sh_B2;
    for (int i = tid; i < A_TOTAL; i += 256) {
      u32 u = sb_of(i);
      if ((u >> 19) == B) {
        u32 sb2 = (u >> 7) & 0xFFFu;
        if (sb2 > B2) {
          u32 p = atomicAdd(&sh_cA, 1u);
          if (p < 5120u) listA[p] = pack_key(u, (u32)i);
        } else if (sb2 == B2) {
          u32 p = atomicAdd(&sh_cE, 1u);
          if (p < 2048u) listE[p] = pack_key(u, (u32)i);
        }
      }
    }
    __syncthreads();
    g = sh_cA; h = sh_cE; if (h > 2048u) h = 2048u;
  }
  if (g > 5120u) g = 5120u;
  u32 R = (g < KTOP) ? (KTOP - g) : 0u; if (R > h) R = h;

  u64 ak[20];
  #pragma unroll
  for (int r = 0; r < 20; ++r) {
    u32 s2 = (u32)tid + (u32)r * 256u;
    u64 kp = (s2 < g) ? listA[s2] : 0ull;
    if (kp < thrpack) kp = 0ull;
    ak[r] = kp;
  }
  __syncthreads();
  float4* box_s = (float4*)big;
  u32* cntArr = (u32*)big;

  const float LO0  = 0.04f;
  const float INV0 = 4096.0f / (1.001f - 0.04f);

  for (int seg = 0; seg < 7200; ++seg) {
    __syncthreads();
    if (sh_w >= MAXT || sh_done) break;
    u64 minPrev = sh_minPrev;

    int digLvl = 0;
    u32 A_B0 = 0, A_B1 = 0;
    float lo1 = 0.f, inv1 = 0.f;
    u64 kMask = 0, kPref = 0;
    int m1shift = 32;
    int selMode = -1;
    u32 selB = 0;
    u32 C = 0;
    bool fromE = false;

    for (int lvl = 0; lvl < 8; ++lvl) {
      for (int i = tid; i < 4096; i += 256) histL[i] = 0;
      __syncthreads();
      #pragma unroll
      for (int r = 0; r < 20; ++r) {
        u64 k = ak[r];
        if (!k || k >= minPrev) continue;
        float s = __uint_as_float((u32)(k >> 32));
        if (digLvl >= 1) { int d0 = (int)((s - LO0) * INV0); d0 = min(max(d0, 0), 4095); if ((u32)d0 != A_B0) continue; }
        if (digLvl >= 2) { int d1 = (int)((s - lo1) * inv1); d1 = min(max(d1, 0), 4095); if ((u32)d1 != A_B1) continue; }
        if (digLvl >= 3 && ((k & kMask) != kPref)) continue;
        u32 d;
        if (digLvl == 0)      { int t0 = (int)((s - LO0) * INV0); d = (u32)min(max(t0, 0), 4095); }
        else if (digLvl == 1) { int t1 = (int)((s - lo1) * inv1); d = (u32)min(max(t1, 0), 4095); }
        else                  d = (u32)((k >> m1shift) & 0xFFFull);
        atomicAdd(&histL[d], 1u);
      }
      __syncthreads();
      if (tid < 64) {
        u32 Bx, ix, ax, tx;
        cut4096w(histL, 1024u, tid, Bx, ix, ax, tx);
        if (tid == 0) { sh_B = Bx; sh_incl = ix; sh_above = ax; sh_total = tx; }
      }
      __syncthreads();
      u32 total = sh_total, incl = sh_incl, above = sh_above, Bx = sh_B;
      if (total == 0u)   { fromE = true; break; }
      if (total < 1024u) { selMode = 0; C = total; break; }
      if (incl <= 2048u) { selMode = 1; selB = Bx; C = incl; break; }
      if (above > 0u)    { selMode = 2; selB = Bx; C = above; break; }
      if (digLvl == 0) {
        A_B0 = Bx;
        lo1 = LO0 + (float)Bx / INV0;
        inv1 = INV0 * 4096.0f;
        digLvl = 1;
      } else if (digLvl == 1) {
        A_B1 = Bx;
        digLvl = 2; m1shift = 32;
      } else {
        kPref |= ((u64)Bx << m1shift);
        kMask |= (0xFFFull << m1shift);
        m1shift -= 12;
        digLvl++;
      }
      __syncthreads();
    }

    if (fromE) {
      if (!sh_eSorted) {
        bitonic_desc(listE, h, tid, 256);
        if (tid == 0) {
          u32 lo = 0, hi2 = h;
          while (lo < hi2) { u32 mid = (lo + hi2) >> 1; if (listE[mid] >= thrpack) lo = mid + 1; else hi2 = mid; }
          sh_Rthr = (R < lo) ? R : lo;
          sh_eSorted = 1;
        }
        __syncthreads();
      }
      u32 eidx = sh_eidx;
      u32 take = (sh_Rthr > eidx) ? (sh_Rthr - eidx) : 0u;
      if (take > 2048u) take = 2048u;
      if (take == 0u) { if (tid == 0) sh_done = 1; continue; }
      for (u32 i = tid; i < take; i += 256) key_s[i] = listE[eidx + i];
      C = take;
      if (tid == 0) sh_eidx = eidx + take;
    } else {
      u32 hloc[16];
      {
        int t0 = tid << 4;
        u32 ssum = 0;
        #pragma unroll
        for (int j = 0; j < 16; ++j) { hloc[j] = histL[t0 + j]; ssum += hloc[j]; }
        int wl = tid & 63, wid = tid >> 6;
        u32 suf = ssum;
        #pragma unroll
        for (int off = 1; off < 64; off <<= 1) {
          u32 v = __shfl_down(suf, off, 64);
          if (wl < 64 - off) suf += v;
        }
        if (wl == 0) wtot[wid] = suf;
        __syncthreads();
        u32 cross = 0;
        for (int w2 = wid + 1; w2 < 4; ++w2) cross += wtot[w2];
        u32 run = (suf - ssum) + cross;
        #pragma unroll
        for (int j = 15; j >= 0; --j) { u32 base2 = run; run += hloc[j]; histL[t0 + j] = base2; }
      }
      for (int i = tid; i < 4096; i += 256) cntArr[i] = 0;
      if (tid == 0) sh_bigF = 0;
      __syncthreads();
      #pragma unroll
      for (int r = 0; r < 20; ++r) {
        u64 k = ak[r];
        if (!k || k >= minPrev) continue;
        float s = __uint_as_float((u32)(k >> 32));
        if (digLvl >= 1) { int d0 = (int)((s - LO0) * INV0); d0 = min(max(d0, 0), 4095); if ((u32)d0 != A_B0) continue; }
        if (digLvl >= 2) { int d1 = (int)((s - lo1) * inv1); d1 = min(max(d1, 0), 4095); if ((u32)d1 != A_B1) continue; }
        if (digLvl >= 3 && ((k & kMask) != kPref)) continue;
        u32 d;
        if (digLvl == 0)      { int t0x = (int)((s - LO0) * INV0); d = (u32)min(max(t0x, 0), 4095); }
        else if (digLvl == 1) { int t1x = (int)((s - lo1) * inv1); d = (u32)min(max(t1x, 0), 4095); }
        else                  d = (u32)((k >> m1shift) & 0xFFFull);
        if (selMode == 1)      { if (d < selB) continue; }
        else if (selMode == 2) { if (d <= selB) continue; }
        u32 pos = histL[d] + atomicAdd(&cntArr[d], 1u);
        if (pos < 2048u) key_s[pos] = k;
      }
      __syncthreads();
      {
        int t0 = tid << 4;
        for (int j = 0; j < 16; ++j) {
          u32 bkt = (u32)(t0 + j);
          u32 cc = cntArr[bkt];
          if (cc >= 2u) {
            if (cc <= 48u) {
              u32 basep = histL[bkt];
              for (u32 a2 = 1; a2 < cc; ++a2) {
                u64 kv = key_s[basep + a2];
                int bi = (int)a2 - 1;
                while (bi >= 0 && key_s[basep + bi] < kv) { key_s[basep + bi + 1] = key_s[basep + bi]; --bi; }
                key_s[basep + bi + 1] = kv;
              }
            } else sh_bigF = 1;
          }
        }
      }
      __syncthreads();
      if (sh_bigF) bitonic_desc(key_s, C, tid, 256);
      if (tid == 0) sh_minPrev = key_s[C - 1];
    }
    __syncthreads();

    for (u32 p = tid; p < C; p += 256) {
      u32 idx = 0xFFFFFFFFu - (u32)(key_s[p] & 0xFFFFFFFFull);
      box_s[p] = boxes4[bbase + idx];
    }
    __syncthreads();

    if (tid < 64) {
      int w = lazy_scan(key_s, box_s, C, wbox, outS, outB, (int)sh_w, tid);
      if (tid == 0) sh_w = (u32)w;
    }
  }

  __syncthreads();
  u32 w = sh_w;
  for (u32 p = w + (u32)tid; p < MAXT; p += 256) {
    outS[p] = -1.0f;
    *(float4*)(outB + p * 4) = make_float4(0.f, 0.f, 0.f, 0.f);
  }
}

// ---------------- final per-batch top-100: radix rank-select ----------------
__global__ __launch_bounds__(256) void merge_kernel(
    const float* __restrict__ nms_s, const float* __restrict__ nms_b,
    float* __restrict__ out_b, float* __restrict__ out_s,
    float* __restrict__ out_c, float* __restrict__ out_v)
{
  __shared__ u64 keys[NCLS * MAXT];   // 72 KB
  __shared__ u32 hist[4096];          // 16 KB
  __shared__ u64 sel[640];
  __shared__ u32 sh_cnt, sh_valid;
  __shared__ u32 sh_B, sh_incl, sh_above, sh_total;

  int b = blockIdx.x, tid = threadIdx.x;
  const int NTOT = NCLS * MAXT;

  for (int i = tid; i < NTOT; i += 256) {
    float s = nms_s[(size_t)b * NTOT + i];
    u32 u = __float_as_uint(s);
    u = (u & 0x80000000u) ? ~u : (u | 0x80000000u);
    keys[i] = ((u64)u << 32) | (u64)(0xFFFFFFFFu - (u32)i);
  }
  if (tid == 0) { sh_cnt = 0; sh_valid = 0; }

  u64 prefVal = 0;
  u64 T = 0;
  u32 need = MAXT;
  const int shifts[6] = {52, 40, 28, 16, 4, 0};
  const int widths[6] = {12, 12, 12, 12, 12, 4};
  for (int lvl = 0; lvl < 6; ++lvl) {
    int s = shifts[lvl], w = widths[lvl];
    for (int i = tid; i < 4096; i += 256) hist[i] = 0;
    __syncthreads();
    u32 dmask = (1u << w) - 1u;
    for (int i = tid; i < NTOT; i += 256) {
      u64 k = keys[i];
      if (lvl > 0 && (k >> (s + w)) != (prefVal >> (s + w))) continue;
      atomicAdd(&hist[(u32)((k >> s) & dmask)], 1u);
    }
    __syncthreads();
    if (tid < 64) {
      u32 Bx, ix, ax, tx;
      cut4096w(hist, need, tid, Bx, ix, ax, tx);
      if (tid == 0) { sh_B = Bx; sh_incl = ix; sh_above = ax; sh_total = tx; }
    }
    __syncthreads();
    u32 B = sh_B, incl = sh_incl, above = sh_above;
    if (incl <= 512u || lvl == 5) {
      T = prefVal | ((u64)B << s);
      break;
    }
    prefVal |= ((u64)B << s);
    need -= above;
  }
  __syncthreads();

  for (int i = tid; i < NTOT; i += 256) {
    u64 k = keys[i];
    if (k >= T) {
      u32 p = atomicAdd(&sh_cnt, 1u);
      if (p < 640u) sel[p] = k;
    }
  }
  __syncthreads();
  u32 cnt = sh_cnt; if (cnt > 640u) cnt = 640u;

  for (u32 j = tid; j < cnt; j += 256) {
    u64 kj = sel[j];
    u32 r = 0;
    for (u32 i = 0; i < cnt; ++i) r += (sel[i] > kj) ? 1u : 0u;
    if (r < (u32)MAXT) {
      u32 u = (u32)(kj >> 32);
      u32 bits = (u & 0x80000000u) ? (u ^ 0x80000000u) : ~u;
      float sc = __uint_as_float(bits);
      u32 flat = 0xFFFFFFFFu - (u32)(kj & 0xFFFFFFFFull);
      int cls = (int)(flat / MAXT), pos = (int)(flat % MAXT);
      out_s[b * MAXT + r] = sc;
      out_c[b * MAXT + r] = (float)(cls + 1);
      *(float4*)(out_b + ((size_t)b * MAXT + r) * 4) =
          *(const float4*)(nms_b + (((size_t)b * NCLS + cls) * MAXT + pos) * 4);
      if (sc > -1.0f) atomicAdd(&sh_valid, 1u);
    }
  }
  __syncthreads();
  if (tid == 0) out_v[b] = (float)sh_valid;
}

extern "C" void kernel_launch(void* const* d_in, const int* in_sizes, int n_in,
                              void* d_out, int out_size, void* d_ws, size_t ws_size,
                              hipStream_t stream)
{
  const float* box[5]; const float* cls[5]; const float* anc[5];
  bool interleaved = (in_sizes[1] == 2 * 57600 * 91);   // setup_inputs dict order
  if (interleaved) {
    for (int l = 0; l < 5; ++l) {
      box[l] = (const float*)d_in[3 * l + 0];
      cls[l] = (const float*)d_in[3 * l + 1];
      anc[l] = (const float*)d_in[3 * l + 2];
    }
  } else {
    for (int l = 0; l < 5; ++l) {
      box[l] = (const float*)d_in[l];
      cls[l] = (const float*)d_in[5 + l];
      anc[l] = (const float*)d_in[10 + l];
    }
  }
  const float* img = (const float*)d_in[15];

  float* ws = (float*)d_ws;
  float* boxes_ws = ws;                              // 613800 f
  u32*   cnt_pad  = (u32*)(boxes_ws + 613800);       // 180*64 u32 (256B-strided counters)
  u64*   listT_g  = (u64*)(cnt_pad + 180 * 64);      // 180*2048 u64
  float* nms_s    = (float*)(listT_g + 180 * 2048);  // 18000 f
  float* nms_b    = nms_s + 18000;                   // 72000 f

  decode_kernel<<<600, 256, 0, stream>>>(
      box[0], box[1], box[2], box[3], box[4],
      anc[0], anc[1], anc[2], anc[3], anc[4], img, boxes_ws, cnt_pad);

  collect_kernel<<<1710, 256, 0, stream>>>(cls[0], cls[1], cls[2], cls[3], cls[4],
                                           listT_g, cnt_pad);

  nms_kernel<<<180, 256, 0, stream>>>(cls[0], cls[1], cls[2], cls[3], cls[4],
                                      boxes_ws, listT_g, cnt_pad, nms_s, nms_b);

  float* out_b = (float*)d_out;  // [2][100][4]
  float* out_s = out_b + 800;    // [2][100]
  float* out_c = out_s + 200;    // [2][100]
  float* out_v = out_c + 200;    // [2]
  merge_kernel<<<2, 256, 0, stream>>>(nms_s, nms_b, out_b, out_s, out_c, out_v);
}

// Round 10
// 119.466 us; speedup vs baseline: 1.5321x; 1.1085x over previous
//
#include <hip/hip_runtime.h>
#include <hip/hip_bf16.h>

typedef unsigned long long u64;
typedef unsigned int u32;

#define A_TOTAL 76725
#define NCLS 90
#define KTOP 5000u
#define MAXT 100
#define KTHR 0x3D4CCCCDu         /* bits of 0.05f */
#define TCAP 2048u               /* per-lane candidate list capacity */
#define NSEL 384u                /* fast-path sorted-prefix size */

__device__ __forceinline__ u64 pack_key(u32 k, u32 i) {
  return ((u64)k << 32) | (u64)(0xFFFFFFFFu - i);
}

__device__ __forceinline__ int dig05(u64 k) {   // digest for s in [0.5,1.0], monotone
  float s = __uint_as_float((u32)(k >> 32));
  int d = (int)((s - 0.5f) * 8175.0f);
  return min(max(d, 0), 4095);
}

// Full wave-0 cut with totals: B = smallest bucket with count(>=B) >= need.
__device__ __forceinline__ void cut4096w(const u32* hh, u32 need, int wl,
                                         u32& B, u32& incl, u32& above, u32& total) {
  int lo = wl << 6;
  u32 s = 0;
  #pragma unroll
  for (int j = 0; j < 64; ++j) s += hh[lo + j];
  u32 suf = s;
  #pragma unroll
  for (int off = 1; off < 64; off <<= 1) {
    u32 v = __shfl_down(suf, off, 64);
    if (wl < 64 - off) suf += v;
  }
  total = __shfl(suf, 0, 64);
  if (total < need) { B = 0; incl = total; above = 0; return; }
  u32 sufnext = suf - s;
  bool cross = (suf >= need) && (sufnext < need);
  u64 bal = __ballot(cross);
  int gl = (int)__ffsll((unsigned long long)bal) - 1;
  int glo = gl << 6;
  u32 aboveG = __shfl(sufnext, gl, 64);
  u32 hb = hh[glo + wl];
  u32 sufb = hb;
  #pragma unroll
  for (int off = 1; off < 64; off <<= 1) {
    u32 v = __shfl_down(sufb, off, 64);
    if (wl < 64 - off) sufb += v;
  }
  bool c2 = (aboveG + sufb >= need) && (aboveG + sufb - hb < need);
  u64 bal2 = __ballot(c2);
  int jB = (int)__ffsll((unsigned long long)bal2) - 1;
  B = (u32)(glo + jB);
  incl = aboveG + __shfl(sufb, jB, 64);
  above = incl - __shfl(hb, jB, 64);
}

// Block-cooperative descending bitonic sort of a[0..n) padded to pow2 with 0.
__device__ __forceinline__ void bitonic_desc(u64* a, u32 n, int tid, int nth) {
  u32 P = 2; while (P < n) P <<= 1;
  for (u32 i = tid; i < P; i += nth) if (i >= n) a[i] = 0ULL;
  __syncthreads();
  for (u32 kk = 2; kk <= P; kk <<= 1) {
    for (u32 jj = kk >> 1; jj; jj >>= 1) {
      for (u32 i = tid; i < P; i += nth) {
        u32 ixj = i ^ jj;
        if (ixj > i) {
          u64 x = a[i], y = a[ixj];
          bool up = ((i & kk) == 0);
          if (up ? (x < y) : (x > y)) { a[i] = y; a[ixj] = x; }
        }
      }
      __syncthreads();
    }
  }
}

// Wave-level lazy greedy NMS scan; boxes fetched from GLOBAL on demand.
// All 64 lanes of one wave call. Returns updated w; *endCur = final cur.
__device__ __forceinline__ int lazy_scan_g(const u64* key_s, const float4* boxes4, size_t bbase,
                                           int C, float4* wbox, float* outS, float* outB,
                                           int w, int wl, int* endCur) {
  int cur = 0;
  while (w < MAXT && cur < C) {
    int p = cur + wl;
    bool alive = (p < C);
    u64 kk = alive ? key_s[p] : 0ull;
    float4 mybox = make_float4(0.f, 0.f, 0.f, 0.f);
    if (alive) {
      u32 idx = 0xFFFFFFFFu - (u32)(kk & 0xFFFFFFFFull);
      mybox = boxes4[bbase + idx];
    }
    float myarea = alive ? (mybox.z - mybox.x) * (mybox.w - mybox.y) : 0.f;
    for (int j = 0; j < w; ++j) {
      if (alive) {
        float4 pb = wbox[j];
        float yy1 = fmaxf(pb.x, mybox.x), xx1 = fmaxf(pb.y, mybox.y);
        float yy2 = fminf(pb.z, mybox.z), xx2 = fminf(pb.w, mybox.w);
        float inter = fmaxf(yy2 - yy1, 0.0f) * fmaxf(xx2 - xx1, 0.0f);
        float pa = (pb.z - pb.x) * (pb.w - pb.y);
        if (inter / (pa + myarea - inter + 1e-8f) > 0.3f) alive = false;
      }
    }
    for (;;) {
      u64 bal = __ballot(alive);
      if (bal == 0ull) break;
      int js = (int)__ffsll((unsigned long long)bal) - 1;
      float4 pb;
      pb.x = __shfl(mybox.x, js, 64);
      pb.y = __shfl(mybox.y, js, 64);
      pb.z = __shfl(mybox.z, js, 64);
      pb.w = __shfl(mybox.w, js, 64);
      u64 wk = __shfl(kk, js, 64);
      if (wl == 0) {
        outS[w] = __uint_as_float((u32)(wk >> 32));
        *(float4*)(outB + w * 4) = pb;
        wbox[w] = pb;
      }
      w++;
      if (w >= MAXT) break;
      if (wl <= js) alive = false;
      else if (alive) {
        float yy1 = fmaxf(pb.x, mybox.x), xx1 = fmaxf(pb.y, mybox.y);
        float yy2 = fminf(pb.z, mybox.z), xx2 = fminf(pb.w, mybox.w);
        float inter = fmaxf(yy2 - yy1, 0.0f) * fmaxf(xx2 - xx1, 0.0f);
        float pa = (pb.z - pb.x) * (pb.w - pb.y);
        if (inter / (pa + myarea - inter + 1e-8f) > 0.3f) alive = false;
      }
    }
    cur += 64;
  }
  *endCur = cur;
  return w;
}

// ---------------- fused decode+clip (blocks 0..599) and streaming collect (600..2309) ----------------
__device__ __forceinline__ void coll_elem(int i, float x, int b, int base,
                                          u64* __restrict__ listT_g, u32* __restrict__ cnt_pad) {
  if (x >= 0.0f) {                  // s >= 0.5
    u32 a = (u32)i / 91u;           // compile-time magic-mul
    u32 c = (u32)i - a * 91u;
    if (c != 0u) {
      float s = 1.0f / (1.0f + expf(-x));
      int lane = b * NCLS + (int)c - 1;
      u32 idx = (u32)base + a;
      u32 p = atomicAdd(&cnt_pad[lane * 64], 1u);
      if (p < TCAP) listT_g[(size_t)lane * TCAP + p] = pack_key(__float_as_uint(s), idx);
    }
  }
}

__global__ __launch_bounds__(256) void front_kernel(
    const float* __restrict__ bx0, const float* __restrict__ bx1, const float* __restrict__ bx2,
    const float* __restrict__ bx3, const float* __restrict__ bx4,
    const float* __restrict__ an0, const float* __restrict__ an1, const float* __restrict__ an2,
    const float* __restrict__ an3, const float* __restrict__ an4,
    const float* __restrict__ c3, const float* __restrict__ c4, const float* __restrict__ c5,
    const float* __restrict__ c6, const float* __restrict__ c7,
    const float* __restrict__ img, float* __restrict__ boxes,
    u64* __restrict__ listT_g, u32* __restrict__ cnt_pad)
{
  int blk = blockIdx.x, tid = threadIdx.x;
  if (blk < 600) {
    // ---- decode + clip ----
    int t = blk * 256 + tid;
    if (t >= 2 * A_TOTAL) return;
    int b = t / A_TOTAL, a = t % A_TOTAL;
    const float* bp; const float* ap; int al; int nl;
    if (a < 57600)      { bp = bx0; ap = an0; al = a;          nl = 57600; }
    else if (a < 72000) { bp = bx1; ap = an1; al = a - 57600;  nl = 14400; }
    else if (a < 75600) { bp = bx2; ap = an2; al = a - 72000;  nl = 3600;  }
    else if (a < 76500) { bp = bx3; ap = an3; al = a - 75600;  nl = 900;   }
    else                { bp = bx4; ap = an4; al = a - 76500;  nl = 225;   }
    float4 e  = *(const float4*)(bp + ((size_t)b * nl + al) * 4);
    float4 an = *(const float4*)(ap + ((size_t)b * nl + al) * 4);
    const float CLIP = 4.135166556742356f; // log(1000/16)
    float ah  = an.z - an.x + 1.0f;
    float aw  = an.w - an.y + 1.0f;
    float ayc = an.x + 0.5f * ah;
    float axc = an.y + 0.5f * aw;
    float dh = fminf(e.z, CLIP), dw = fminf(e.w, CLIP);
    float yc = e.x * ah + ayc;
    float xc = e.y * aw + axc;
    float h  = expf(dh) * ah;
    float w  = expf(dw) * aw;
    float ymin = yc - 0.5f * h;
    float xmin = xc - 0.5f * w;
    float ymax = ymin + h - 1.0f;
    float xmax = xmin + w - 1.0f;
    float H = img[b * 2 + 0], W = img[b * 2 + 1];
    float4 o;
    o.x = fminf(fmaxf(ymin, 0.0f), H);
    o.y = fminf(fmaxf(xmin, 0.0f), W);
    o.z = fminf(fmaxf(ymax, 0.0f), H);
    o.w = fminf(fmaxf(xmax, 0.0f), W);
    *(float4*)(boxes + (size_t)t * 4) = o;
    return;
  }
  // ---- streaming collect ----
  int blk2 = blk - 600;
  const float* cls; int n, base, b, loc, J, lvl;
  if (blk2 < 1280)      { lvl = 0; cls = c3; n = 57600; base = 0;     J = 640; int r = blk2;        b = r >= J; loc = b ? r - J : r; }
  else if (blk2 < 1600) { lvl = 1; cls = c4; n = 14400; base = 57600; J = 160; int r = blk2 - 1280; b = r >= J; loc = b ? r - J : r; }
  else if (blk2 < 1680) { lvl = 2; cls = c5; n = 3600;  base = 72000; J = 40;  int r = blk2 - 1600; b = r >= J; loc = b ? r - J : r; }
  else if (blk2 < 1700) { lvl = 3; cls = c6; n = 900;   base = 75600; J = 10;  int r = blk2 - 1680; b = r >= J; loc = b ? r - J : r; }
  else                  { lvl = 4; cls = c7; n = 225;   base = 76500; J = 5;   int r = blk2 - 1700; b = r >= J; loc = b ? r - J : r; }

  if (lvl <= 3) {
    int F4 = n * 91 / 4;
    int chunk = (F4 + J - 1) / J;
    int q0 = loc * chunk;
    int q1 = q0 + chunk; if (q1 > F4) q1 = F4;
    const float4* src4 = (const float4*)(cls + (size_t)b * n * 91);
    for (int q = q0 + tid; q < q1; q += 256) {
      float4 v = src4[q];
      int i0 = q << 2;
      coll_elem(i0,     v.x, b, base, listT_g, cnt_pad);
      coll_elem(i0 + 1, v.y, b, base, listT_g, cnt_pad);
      coll_elem(i0 + 2, v.z, b, base, listT_g, cnt_pad);
      coll_elem(i0 + 3, v.w, b, base, listT_g, cnt_pad);
    }
  } else {
    int F = n * 91;                 // 20475 (not /4-divisible) -> scalar
    int chunk = (F + J - 1) / J;
    int s0 = loc * chunk;
    int s1 = s0 + chunk; if (s1 > F) s1 = F;
    const float* src = cls + (size_t)b * F;
    for (int i = s0 + tid; i < s1; i += 256) coll_elem(i, src[i], b, base, listT_g, cnt_pad);
  }
}

// ---------------- per-lane NMS: rank-select fast path + full-sort mid path + exact fallback ----------------
__global__ __launch_bounds__(256) void nms_kernel(
    const float* __restrict__ c3, const float* __restrict__ c4, const float* __restrict__ c5,
    const float* __restrict__ c6, const float* __restrict__ c7,
    const float* __restrict__ boxes, const u64* __restrict__ listT_g,
    const u32* __restrict__ cnt_pad, float* __restrict__ nms_s, float* __restrict__ nms_b)
{
  __shared__ __align__(16) char big[40960];     // fallback: listA u64[5120] -> cntArr u32[4096]
  __shared__ __align__(16) u64 listE[2048];     // fallback only
  __shared__ u64 key_s[2048];
  __shared__ __align__(16) u32 histL[4096];     // hist; fast path reuses as sel u64[768]
  __shared__ float4 wbox[MAXT];
  __shared__ u32 wtot[4];
  __shared__ u32 sh_flag, sh_mid, sh_bigS, sh_cS;
  __shared__ u64 sh_minPrev;
  __shared__ u32 sh_w, sh_done, sh_eidx, sh_Rthr, sh_eSorted, sh_bigF;
  __shared__ u32 sh_B, sh_incl, sh_above, sh_total, sh_cA, sh_cE, sh_B2;

  int tid = threadIdx.x;
  int lane = blockIdx.x;
  int b = lane / NCLS, c = lane % NCLS;
  const float4* boxes4 = (const float4*)boxes;
  size_t bbase = (size_t)b * A_TOTAL;
  const u64 thrpack = ((u64)KTHR) << 32;

  float* outS = nms_s + (size_t)lane * MAXT;
  float* outB = nms_b + (size_t)lane * MAXT * 4;

  u32 cnt = cnt_pad[lane * 64];
  if (tid == 0) { sh_flag = (cnt > TCAP) ? 1u : 0u; sh_mid = 0; sh_bigS = 0; }
  __syncthreads();

  if (!sh_flag) {
    // ---- load this lane's keys into registers (8/thread) ----
    const u64* LT = listT_g + (size_t)lane * TCAP;
    u64 kr[8];
    #pragma unroll
    for (int r = 0; r < 8; ++r) {
      u32 s = (u32)tid + (u32)r * 256u;
      kr[r] = (s < cnt) ? LT[s] : 0ull;
    }

    // ========== FAST: sorted top-NSEL prefix ==========
    for (int i = tid; i < 4096; i += 256) histL[i] = 0;
    __syncthreads();
    #pragma unroll
    for (int r = 0; r < 8; ++r) if (kr[r]) atomicAdd(&histL[dig05(kr[r])], 1u);
    __syncthreads();
    if (tid < 64) {
      u32 Bx, ix, ax, tx;
      cut4096w(histL, NSEL, tid, Bx, ix, ax, tx);
      if (tid == 0) { sh_B = Bx; sh_incl = ix; sh_total = tx; sh_cS = 0; }
    }
    __syncthreads();
    u32 B = sh_B, incl = sh_incl, total = sh_total;
    bool selAll = (total < NSEL);
    u32 Csel = selAll ? total : incl;
    if (Csel <= 768u) {
      u64* sel = (u64*)histL;     // reuse (cut reads complete; barrier above)
      #pragma unroll
      for (int r = 0; r < 8; ++r) {
        u64 k = kr[r];
        if (k && (selAll || (u32)dig05(k) >= B)) {
          u32 p = atomicAdd(&sh_cS, 1u);
          if (p < 768u) sel[p] = k;
        }
      }
      __syncthreads();
      u32 Cs = sh_cS; if (Cs > 768u) Cs = 768u;
      // rank-by-comparison -> exact descending order (keys unique)
      for (u32 j = tid; j < Cs; j += 256) {
        u64 kj = sel[j];
        u32 rk = 0;
        for (u32 i2 = 0; i2 < Cs; ++i2) rk += (sel[i2] > kj) ? 1u : 0u;
        key_s[rk] = kj;
      }
      __syncthreads();
      if (tid < 64) {
        int ec;
        int w = lazy_scan_g(key_s, boxes4, bbase, (int)Cs, wbox, outS, outB, 0, tid, &ec);
        if (tid == 0) {
          sh_w = (u32)w;
          if (w < MAXT) { if (selAll) sh_flag = 1; else sh_mid = 1; }
          else if (!selAll && ec > (int)Cs - 64) sh_mid = 1;
        }
      }
    } else {
      if (tid == 0) sh_mid = 1;
    }
    __syncthreads();

    // ========== MID: counting-sort ALL s>=0.5 candidates, rescan ==========
    if (sh_mid && !sh_flag) {
      for (int i = tid; i < 4096; i += 256) histL[i] = 0;
      if (tid == 0) sh_bigS = 0;
      __syncthreads();
      #pragma unroll
      for (int r = 0; r < 8; ++r) if (kr[r]) atomicAdd(&histL[dig05(kr[r])], 1u);
      __syncthreads();
      // descending exclusive prefix
      {
        int t0 = tid << 4;
        u32 hloc[16]; u32 ssum = 0;
        #pragma unroll
        for (int j = 0; j < 16; ++j) { hloc[j] = histL[t0 + j]; ssum += hloc[j]; }
        int wl = tid & 63, wid = tid >> 6;
        u32 suf = ssum;
        #pragma unroll
        for (int off = 1; off < 64; off <<= 1) {
          u32 v = __shfl_down(suf, off, 64);
          if (wl < 64 - off) suf += v;
        }
        if (wl == 0) wtot[wid] = suf;
        __syncthreads();
        u32 cross = 0;
        for (int w2 = wid + 1; w2 < 4; ++w2) cross += wtot[w2];
        u32 run = (suf - ssum) + cross;
        #pragma unroll
        for (int j = 15; j >= 0; --j) { u32 b2 = run; run += hloc[j]; histL[t0 + j] = b2; }
      }
      __syncthreads();
      #pragma unroll
      for (int r = 0; r < 8; ++r) {
        u64 k = kr[r];
        if (k) {
          u32 pos = atomicAdd(&histL[dig05(k)], 1u);
          if (pos < TCAP) key_s[pos] = k;
        }
      }
      __syncthreads();
      // per-bucket insertion minisort; bucket d spans [histL[d+1], histL[d])
      {
        int t0 = tid << 4;
        for (int j = 0; j < 16; ++j) {
          u32 d = (u32)(t0 + j);
          u32 end = histL[d];
          u32 start = (d == 4095u) ? 0u : histL[d + 1];
          u32 cc = end - start;
          if (cc >= 2u) {
            if (cc <= 48u) {
              for (u32 a2 = start + 1; a2 < end; ++a2) {
                u64 kv = key_s[a2];
                int bi = (int)a2 - 1;
                while (bi >= (int)start && key_s[bi] < kv) { key_s[bi + 1] = key_s[bi]; --bi; }
                key_s[bi + 1] = kv;
              }
            } else sh_bigS = 1;
          }
        }
      }
      __syncthreads();
      if (sh_bigS) bitonic_desc(key_s, cnt, tid, 256);
      if (tid < 64) {
        int ec;
        int w = lazy_scan_g(key_s, boxes4, bbase, (int)cnt, wbox, outS, outB, 0, tid, &ec);
        if (tid == 0) {
          sh_w = (u32)w;
          if (w < MAXT) sh_flag = 1;   // s>=0.5 pool exhausted -> exact needed
        }
      }
    }
  }
  __syncthreads();
  if (!sh_flag) {
    u32 w = sh_w;
    for (u32 p = w + (u32)tid; p < MAXT; p += 256) {
      outS[p] = -1.0f;
      *(float4*)(outB + p * 4) = make_float4(0.f, 0.f, 0.f, 0.f);
    }
    return;
  }

  // ================= EXACT FALLBACK (rare): rebuild from raw column =================
  auto sb_of = [&](int i) -> u32 {
    const float* p; int al, nl;
    if (i < 57600)      { p = c3; al = i;          nl = 57600; }
    else if (i < 72000) { p = c4; al = i - 57600;  nl = 14400; }
    else if (i < 75600) { p = c5; al = i - 72000;  nl = 3600;  }
    else if (i < 76500) { p = c6; al = i - 75600;  nl = 900;   }
    else                { p = c7; al = i - 76500;  nl = 225;   }
    float x = p[((size_t)b * nl + al) * 91 + (c + 1)];
    float s = 1.0f / (1.0f + expf(-x));
    return __float_as_uint(s);
  };

  u64* listA = (u64*)big;
  for (int i = tid; i < 4096; i += 256) histL[i] = 0;
  if (tid == 0) {
    sh_cA = 0; sh_cE = 0; sh_w = 0; sh_done = 0; sh_eidx = 0; sh_eSorted = 0; sh_minPrev = ~0ull;
  }
  __syncthreads();
  for (int i = tid; i < A_TOTAL; i += 256) atomicAdd(&histL[sb_of(i) >> 19], 1u);
  __syncthreads();
  if (tid < 64) {
    u32 Bx, ix, ax, tx;
    cut4096w(histL, KTOP, tid, Bx, ix, ax, tx);
    if (tid == 0) sh_B = Bx;
  }
  __syncthreads();
  u32 B = sh_B;
  for (int i = tid; i < A_TOTAL; i += 256) {
    u32 u = sb_of(i);
    u32 bkt = u >> 19;
    if (bkt > B) {
      u32 p = atomicAdd(&sh_cA, 1u);
      if (p < 5120u) listA[p] = pack_key(u, (u32)i);
    } else if (bkt == B) {
      u32 p = atomicAdd(&sh_cE, 1u);
      if (p < 2048u) listE[p] = pack_key(u, (u32)i);
    }
  }
  __syncthreads();
  u32 g = sh_cA, h = sh_cE;
  if (h > 2048u) {
    for (int i = tid; i < 4096; i += 256) histL[i] = 0;
    if (tid == 0) sh_cE = 0;
    __syncthreads();
    for (int i = tid; i < A_TOTAL; i += 256) {
      u32 u = sb_of(i);
      if ((u >> 19) == B) atomicAdd(&histL[(u >> 7) & 0xFFFu], 1u);
    }
    __syncthreads();
    u32 R1 = KTOP - g;
    if (tid < 64) {
      u32 Bx, ix, ax, tx;
      cut4096w(histL, R1, tid, Bx, ix, ax, tx);
      if (tid == 0) sh_B2 = Bx;
    }
    __syncthreads();
    u32 B2 = sh_B2;
    for (int i = tid; i < A_TOTAL; i += 256) {
      u32 u = sb_of(i);
      if ((u >> 19) == B) {
        u32 sb2 = (u >> 7) & 0xFFFu;
        if (sb2 > B2) {
          u32 p = atomicAdd(&sh_cA, 1u);
          if (p < 5120u) listA[p] = pack_key(u, (u32)i);
        } else if (sb2 == B2) {
          u32 p = atomicAdd(&sh_cE, 1u);
          if (p < 2048u) listE[p] = pack_key(u, (u32)i);
        }
      }
    }
    __syncthreads();
    g = sh_cA; h = sh_cE; if (h > 2048u) h = 2048u;
  }
  if (g > 5120u) g = 5120u;
  u32 R = (g < KTOP) ? (KTOP - g) : 0u; if (R > h) R = h;

  u64 ak[20];
  #pragma unroll
  for (int r = 0; r < 20; ++r) {
    u32 s2 = (u32)tid + (u32)r * 256u;
    u64 kp = (s2 < g) ? listA[s2] : 0ull;
    if (kp < thrpack) kp = 0ull;
    ak[r] = kp;
  }
  __syncthreads();
  u32* cntArr = (u32*)big;

  const float LO0  = 0.04f;
  const float INV0 = 4096.0f / (1.001f - 0.04f);

  for (int seg = 0; seg < 7200; ++seg) {
    __syncthreads();
    if (sh_w >= MAXT || sh_done) break;
    u64 minPrev = sh_minPrev;

    int digLvl = 0;
    u32 A_B0 = 0, A_B1 = 0;
    float lo1 = 0.f, inv1 = 0.f;
    u64 kMask = 0, kPref = 0;
    int m1shift = 32;
    int selMode = -1;
    u32 selB = 0;
    u32 C = 0;
    bool fromE = false;

    for (int lvl = 0; lvl < 8; ++lvl) {
      for (int i = tid; i < 4096; i += 256) histL[i] = 0;
      __syncthreads();
      #pragma unroll
      for (int r = 0; r < 20; ++r) {
        u64 k = ak[r];
        if (!k || k >= minPrev) continue;
        float s = __uint_as_float((u32)(k >> 32));
        if (digLvl >= 1) { int d0 = (int)((s - LO0) * INV0); d0 = min(max(d0, 0), 4095); if ((u32)d0 != A_B0) continue; }
        if (digLvl >= 2) { int d1 = (int)((s - lo1) * inv1); d1 = min(max(d1, 0), 4095); if ((u32)d1 != A_B1) continue; }
        if (digLvl >= 3 && ((k & kMask) != kPref)) continue;
        u32 d;
        if (digLvl == 0)      { int t0 = (int)((s - LO0) * INV0); d = (u32)min(max(t0, 0), 4095); }
        else if (digLvl == 1) { int t1 = (int)((s - lo1) * inv1); d = (u32)min(max(t1, 0), 4095); }
        else                  d = (u32)((k >> m1shift) & 0xFFFull);
        atomicAdd(&histL[d], 1u);
      }
      __syncthreads();
      if (tid < 64) {
        u32 Bx, ix, ax, tx;
        cut4096w(histL, 1024u, tid, Bx, ix, ax, tx);
        if (tid == 0) { sh_B = Bx; sh_incl = ix; sh_above = ax; sh_total = tx; }
      }
      __syncthreads();
      u32 total = sh_total, incl = sh_incl, above = sh_above, Bx = sh_B;
      if (total == 0u)   { fromE = true; break; }
      if (total < 1024u) { selMode = 0; C = total; break; }
      if (incl <= 2048u) { selMode = 1; selB = Bx; C = incl; break; }
      if (above > 0u)    { selMode = 2; selB = Bx; C = above; break; }
      if (digLvl == 0) {
        A_B0 = Bx;
        lo1 = LO0 + (float)Bx / INV0;
        inv1 = INV0 * 4096.0f;
        digLvl = 1;
      } else if (digLvl == 1) {
        A_B1 = Bx;
        digLvl = 2; m1shift = 32;
      } else {
        kPref |= ((u64)Bx << m1shift);
        kMask |= (0xFFFull << m1shift);
        m1shift -= 12;
        digLvl++;
      }
      __syncthreads();
    }

    if (fromE) {
      if (!sh_eSorted) {
        bitonic_desc(listE, h, tid, 256);
        if (tid == 0) {
          u32 lo = 0, hi2 = h;
          while (lo < hi2) { u32 mid = (lo + hi2) >> 1; if (listE[mid] >= thrpack) lo = mid + 1; else hi2 = mid; }
          sh_Rthr = (R < lo) ? R : lo;
          sh_eSorted = 1;
        }
        __syncthreads();
      }
      u32 eidx = sh_eidx;
      u32 take = (sh_Rthr > eidx) ? (sh_Rthr - eidx) : 0u;
      if (take > 2048u) take = 2048u;
      if (take == 0u) { if (tid == 0) sh_done = 1; continue; }
      for (u32 i = tid; i < take; i += 256) key_s[i] = listE[eidx + i];
      C = take;
      if (tid == 0) sh_eidx = eidx + take;
    } else {
      u32 hloc[16];
      {
        int t0 = tid << 4;
        u32 ssum = 0;
        #pragma unroll
        for (int j = 0; j < 16; ++j) { hloc[j] = histL[t0 + j]; ssum += hloc[j]; }
        int wl = tid & 63, wid = tid >> 6;
        u32 suf = ssum;
        #pragma unroll
        for (int off = 1; off < 64; off <<= 1) {
          u32 v = __shfl_down(suf, off, 64);
          if (wl < 64 - off) suf += v;
        }
        if (wl == 0) wtot[wid] = suf;
        __syncthreads();
        u32 cross = 0;
        for (int w2 = wid + 1; w2 < 4; ++w2) cross += wtot[w2];
        u32 run = (suf - ssum) + cross;
        #pragma unroll
        for (int j = 15; j >= 0; --j) { u32 base2 = run; run += hloc[j]; histL[t0 + j] = base2; }
      }
      for (int i = tid; i < 4096; i += 256) cntArr[i] = 0;
      if (tid == 0) sh_bigF = 0;
      __syncthreads();
      #pragma unroll
      for (int r = 0; r < 20; ++r) {
        u64 k = ak[r];
        if (!k || k >= minPrev) continue;
        float s = __uint_as_float((u32)(k >> 32));
        if (digLvl >= 1) { int d0 = (int)((s - LO0) * INV0); d0 = min(max(d0, 0), 4095); if ((u32)d0 != A_B0) continue; }
        if (digLvl >= 2) { int d1 = (int)((s - lo1) * inv1); d1 = min(max(d1, 0), 4095); if ((u32)d1 != A_B1) continue; }
        if (digLvl >= 3 && ((k & kMask) != kPref)) continue;
        u32 d;
        if (digLvl == 0)      { int t0x = (int)((s - LO0) * INV0); d = (u32)min(max(t0x, 0), 4095); }
        else if (digLvl == 1) { int t1x = (int)((s - lo1) * inv1); d = (u32)min(max(t1x, 0), 4095); }
        else                  d = (u32)((k >> m1shift) & 0xFFFull);
        if (selMode == 1)      { if (d < selB) continue; }
        else if (selMode == 2) { if (d <= selB) continue; }
        u32 pos = histL[d] + atomicAdd(&cntArr[d], 1u);
        if (pos < 2048u) key_s[pos] = k;
      }
      __syncthreads();
      {
        int t0 = tid << 4;
        for (int j = 0; j < 16; ++j) {
          u32 bkt = (u32)(t0 + j);
          u32 cc = cntArr[bkt];
          if (cc >= 2u) {
            if (cc <= 48u) {
              u32 basep = histL[bkt];
              for (u32 a2 = 1; a2 < cc; ++a2) {
                u64 kv = key_s[basep + a2];
                int bi = (int)a2 - 1;
                while (bi >= 0 && key_s[basep + bi] < kv) { key_s[basep + bi + 1] = key_s[basep + bi]; --bi; }
                key_s[basep + bi + 1] = kv;
              }
            } else sh_bigF = 1;
          }
        }
      }
      __syncthreads();
      if (sh_bigF) bitonic_desc(key_s, C, tid, 256);
      if (tid == 0) sh_minPrev = key_s[C - 1];
    }
    __syncthreads();

    if (tid < 64) {
      int ec;
      int w = lazy_scan_g(key_s, boxes4, bbase, (int)C, wbox, outS, outB, (int)sh_w, tid, &ec);
      if (tid == 0) sh_w = (u32)w;
    }
  }

  __syncthreads();
  u32 w = sh_w;
  for (u32 p = w + (u32)tid; p < MAXT; p += 256) {
    outS[p] = -1.0f;
    *(float4*)(outB + p * 4) = make_float4(0.f, 0.f, 0.f, 0.f);
  }
}

// ---------------- final per-batch top-100: radix rank-select ----------------
__global__ __launch_bounds__(256) void merge_kernel(
    const float* __restrict__ nms_s, const float* __restrict__ nms_b,
    float* __restrict__ out_b, float* __restrict__ out_s,
    float* __restrict__ out_c, float* __restrict__ out_v)
{
  __shared__ u64 keys[NCLS * MAXT];   // 72 KB
  __shared__ u32 hist[4096];          // 16 KB
  __shared__ u64 sel[640];
  __shared__ u32 sh_cnt, sh_valid;
  __shared__ u32 sh_B, sh_incl, sh_above, sh_total;

  int b = blockIdx.x, tid = threadIdx.x;
  const int NTOT = NCLS * MAXT;

  for (int i = tid; i < NTOT; i += 256) {
    float s = nms_s[(size_t)b * NTOT + i];
    u32 u = __float_as_uint(s);
    u = (u & 0x80000000u) ? ~u : (u | 0x80000000u);
    keys[i] = ((u64)u << 32) | (u64)(0xFFFFFFFFu - (u32)i);
  }
  if (tid == 0) { sh_cnt = 0; sh_valid = 0; }

  u64 prefVal = 0;
  u64 T = 0;
  u32 need = MAXT;
  const int shifts[6] = {52, 40, 28, 16, 4, 0};
  const int widths[6] = {12, 12, 12, 12, 12, 4};
  for (int lvl = 0; lvl < 6; ++lvl) {
    int s = shifts[lvl], w = widths[lvl];
    for (int i = tid; i < 4096; i += 256) hist[i] = 0;
    __syncthreads();
    u32 dmask = (1u << w) - 1u;
    for (int i = tid; i < NTOT; i += 256) {
      u64 k = keys[i];
      if (lvl > 0 && (k >> (s + w)) != (prefVal >> (s + w))) continue;
      atomicAdd(&hist[(u32)((k >> s) & dmask)], 1u);
    }
    __syncthreads();
    if (tid < 64) {
      u32 Bx, ix, ax, tx;
      cut4096w(hist, need, tid, Bx, ix, ax, tx);
      if (tid == 0) { sh_B = Bx; sh_incl = ix; sh_above = ax; sh_total = tx; }
    }
    __syncthreads();
    u32 B = sh_B, incl = sh_incl, above = sh_above;
    if (incl <= 512u || lvl == 5) {
      T = prefVal | ((u64)B << s);
      break;
    }
    prefVal |= ((u64)B << s);
    need -= above;
  }
  __syncthreads();

  for (int i = tid; i < NTOT; i += 256) {
    u64 k = keys[i];
    if (k >= T) {
      u32 p = atomicAdd(&sh_cnt, 1u);
      if (p < 640u) sel[p] = k;
    }
  }
  __syncthreads();
  u32 cnt = sh_cnt; if (cnt > 640u) cnt = 640u;

  for (u32 j = tid; j < cnt; j += 256) {
    u64 kj = sel[j];
    u32 r = 0;
    for (u32 i = 0; i < cnt; ++i) r += (sel[i] > kj) ? 1u : 0u;
    if (r < (u32)MAXT) {
      u32 u = (u32)(kj >> 32);
      u32 bits = (u & 0x80000000u) ? (u ^ 0x80000000u) : ~u;
      float sc = __uint_as_float(bits);
      u32 flat = 0xFFFFFFFFu - (u32)(kj & 0xFFFFFFFFull);
      int cls = (int)(flat / MAXT), pos = (int)(flat % MAXT);
      out_s[b * MAXT + r] = sc;
      out_c[b * MAXT + r] = (float)(cls + 1);
      *(float4*)(out_b + ((size_t)b * MAXT + r) * 4) =
          *(const float4*)(nms_b + (((size_t)b * NCLS + cls) * MAXT + pos) * 4);
      if (sc > -1.0f) atomicAdd(&sh_valid, 1u);
    }
  }
  __syncthreads();
  if (tid == 0) out_v[b] = (float)sh_valid;
}

extern "C" void kernel_launch(void* const* d_in, const int* in_sizes, int n_in,
                              void* d_out, int out_size, void* d_ws, size_t ws_size,
                              hipStream_t stream)
{
  const float* box[5]; const float* cls[5]; const float* anc[5];
  bool interleaved = (in_sizes[1] == 2 * 57600 * 91);   // setup_inputs dict order
  if (interleaved) {
    for (int l = 0; l < 5; ++l) {
      box[l] = (const float*)d_in[3 * l + 0];
      cls[l] = (const float*)d_in[3 * l + 1];
      anc[l] = (const float*)d_in[3 * l + 2];
    }
  } else {
    for (int l = 0; l < 5; ++l) {
      box[l] = (const float*)d_in[l];
      cls[l] = (const float*)d_in[5 + l];
      anc[l] = (const float*)d_in[10 + l];
    }
  }
  const float* img = (const float*)d_in[15];

  float* ws = (float*)d_ws;
  float* boxes_ws = ws;                              // 613800 f
  u32*   cnt_pad  = (u32*)(boxes_ws + 613800);       // 180*64 u32 (256B-strided counters)
  u64*   listT_g  = (u64*)(cnt_pad + 180 * 64);      // 180*2048 u64
  float* nms_s    = (float*)(listT_g + 180 * 2048);  // 18000 f
  float* nms_b    = nms_s + 18000;                   // 72000 f

  hipMemsetAsync(cnt_pad, 0, 180 * 64 * sizeof(u32), stream);

  front_kernel<<<2310, 256, 0, stream>>>(
      box[0], box[1], box[2], box[3], box[4],
      anc[0], anc[1], anc[2], anc[3], anc[4],
      cls[0], cls[1], cls[2], cls[3], cls[4],
      img, boxes_ws, listT_g, cnt_pad);

  nms_kernel<<<180, 256, 0, stream>>>(cls[0], cls[1], cls[2], cls[3], cls[4],
                                      boxes_ws, listT_g, cnt_pad, nms_s, nms_b);

  float* out_b = (float*)d_out;  // [2][100][4]
  float* out_s = out_b + 800;    // [2][100]
  float* out_c = out_s + 200;    // [2][100]
  float* out_v = out_c + 200;    // [2]
  merge_kernel<<<2, 256, 0, stream>>>(nms_s, nms_b, out_b, out_s, out_c, out_v);
}

// Round 11
// 114.884 us; speedup vs baseline: 1.5932x; 1.0399x over previous
//
#include <hip/hip_runtime.h>
#include <hip/hip_bf16.h>

typedef unsigned long long u64;
typedef unsigned int u32;

#define A_TOTAL 76725
#define NCLS 90
#define KTOP 5000u
#define MAXT 100
#define KTHR 0x3D4CCCCDu         /* bits of 0.05f */
#define TCAP 2048u               /* per-lane candidate capacity (total) */
#define SCAP 512u                /* per-slice capacity */
#define NSEL 384u                /* fast-path sorted-prefix size */

__device__ __forceinline__ u64 pack_key(u32 k, u32 i) {
  return ((u64)k << 32) | (u64)(0xFFFFFFFFu - i);
}

__device__ __forceinline__ int dig05(u64 k) {   // digest for s in [0.5,1.0], monotone
  float s = __uint_as_float((u32)(k >> 32));
  int d = (int)((s - 0.5f) * 8175.0f);
  return min(max(d, 0), 4095);
}

// Full wave-0 cut with totals: B = smallest bucket with count(>=B) >= need.
__device__ __forceinline__ void cut4096w(const u32* hh, u32 need, int wl,
                                         u32& B, u32& incl, u32& above, u32& total) {
  int lo = wl << 6;
  u32 s = 0;
  #pragma unroll
  for (int j = 0; j < 64; ++j) s += hh[lo + j];
  u32 suf = s;
  #pragma unroll
  for (int off = 1; off < 64; off <<= 1) {
    u32 v = __shfl_down(suf, off, 64);
    if (wl < 64 - off) suf += v;
  }
  total = __shfl(suf, 0, 64);
  if (total < need) { B = 0; incl = total; above = 0; return; }
  u32 sufnext = suf - s;
  bool cross = (suf >= need) && (sufnext < need);
  u64 bal = __ballot(cross);
  int gl = (int)__ffsll((unsigned long long)bal) - 1;
  int glo = gl << 6;
  u32 aboveG = __shfl(sufnext, gl, 64);
  u32 hb = hh[glo + wl];
  u32 sufb = hb;
  #pragma unroll
  for (int off = 1; off < 64; off <<= 1) {
    u32 v = __shfl_down(sufb, off, 64);
    if (wl < 64 - off) sufb += v;
  }
  bool c2 = (aboveG + sufb >= need) && (aboveG + sufb - hb < need);
  u64 bal2 = __ballot(c2);
  int jB = (int)__ffsll((unsigned long long)bal2) - 1;
  B = (u32)(glo + jB);
  incl = aboveG + __shfl(sufb, jB, 64);
  above = incl - __shfl(hb, jB, 64);
}

// Block-cooperative descending bitonic sort of a[0..n) padded to pow2 with 0.
__device__ __forceinline__ void bitonic_desc(u64* a, u32 n, int tid, int nth) {
  u32 P = 2; while (P < n) P <<= 1;
  for (u32 i = tid; i < P; i += nth) if (i >= n) a[i] = 0ULL;
  __syncthreads();
  for (u32 kk = 2; kk <= P; kk <<= 1) {
    for (u32 jj = kk >> 1; jj; jj >>= 1) {
      for (u32 i = tid; i < P; i += nth) {
        u32 ixj = i ^ jj;
        if (ixj > i) {
          u64 x = a[i], y = a[ixj];
          bool up = ((i & kk) == 0);
          if (up ? (x < y) : (x > y)) { a[i] = y; a[ixj] = x; }
        }
      }
      __syncthreads();
    }
  }
}

// Wave-level lazy greedy NMS scan; boxes fetched from GLOBAL on demand.
// IEEE division only when inter > 0 (exactly equivalent: 0/den = 0 <= 0.3).
__device__ __forceinline__ int lazy_scan_g(const u64* key_s, const float4* boxes4, size_t bbase,
                                           int C, float4* wbox, float* outS, float* outB,
                                           int w, int wl) {
  int cur = 0;
  while (w < MAXT && cur < C) {
    int p = cur + wl;
    bool alive = (p < C);
    u64 kk = alive ? key_s[p] : 0ull;
    float4 mybox = make_float4(0.f, 0.f, 0.f, 0.f);
    if (alive) {
      u32 idx = 0xFFFFFFFFu - (u32)(kk & 0xFFFFFFFFull);
      mybox = boxes4[bbase + idx];
    }
    float myarea = alive ? (mybox.z - mybox.x) * (mybox.w - mybox.y) : 0.f;
    for (int j = 0; j < w; ++j) {
      if (alive) {
        float4 pb = wbox[j];
        float yy1 = fmaxf(pb.x, mybox.x), xx1 = fmaxf(pb.y, mybox.y);
        float yy2 = fminf(pb.z, mybox.z), xx2 = fminf(pb.w, mybox.w);
        float inter = fmaxf(yy2 - yy1, 0.0f) * fmaxf(xx2 - xx1, 0.0f);
        if (inter > 0.0f) {
          float pa = (pb.z - pb.x) * (pb.w - pb.y);
          if (inter / (pa + myarea - inter + 1e-8f) > 0.3f) alive = false;
        }
      }
    }
    for (;;) {
      u64 bal = __ballot(alive);
      if (bal == 0ull) break;
      int js = (int)__ffsll((unsigned long long)bal) - 1;
      float4 pb;
      pb.x = __shfl(mybox.x, js, 64);
      pb.y = __shfl(mybox.y, js, 64);
      pb.z = __shfl(mybox.z, js, 64);
      pb.w = __shfl(mybox.w, js, 64);
      u64 wk = __shfl(kk, js, 64);
      if (wl == 0) {
        outS[w] = __uint_as_float((u32)(wk >> 32));
        *(float4*)(outB + w * 4) = pb;
        wbox[w] = pb;
      }
      w++;
      if (w >= MAXT) break;
      if (wl <= js) alive = false;
      else if (alive) {
        float yy1 = fmaxf(pb.x, mybox.x), xx1 = fmaxf(pb.y, mybox.y);
        float yy2 = fminf(pb.z, mybox.z), xx2 = fminf(pb.w, mybox.w);
        float inter = fmaxf(yy2 - yy1, 0.0f) * fmaxf(xx2 - xx1, 0.0f);
        if (inter > 0.0f) {
          float pa = (pb.z - pb.x) * (pb.w - pb.y);
          if (inter / (pa + myarea - inter + 1e-8f) > 0.3f) alive = false;
        }
      }
    }
    cur += 64;
  }
  return w;
}

// ---------------- fused decode+clip (blocks 0..599) and streaming collect (600..4019) ----------------
__device__ __forceinline__ void coll_elem(int i, float x, int b, int base, int slice,
                                          u64* __restrict__ listT_g, u32* __restrict__ cnt_pad) {
  if (x >= 0.0f) {                  // s >= 0.5
    u32 a = (u32)i / 91u;           // compile-time magic-mul
    u32 c = (u32)i - a * 91u;
    if (c != 0u) {
      float s = 1.0f / (1.0f + expf(-x));
      int lane = b * NCLS + (int)c - 1;
      u32 idx = (u32)base + a;
      u32 p = atomicAdd(&cnt_pad[lane * 128 + slice * 16], 1u);
      if (p < SCAP) listT_g[(((size_t)lane * 8 + slice) << 9) + p] = pack_key(__float_as_uint(s), idx);
    }
  }
}

__global__ __launch_bounds__(256) void front_kernel(
    const float* __restrict__ bx0, const float* __restrict__ bx1, const float* __restrict__ bx2,
    const float* __restrict__ bx3, const float* __restrict__ bx4,
    const float* __restrict__ an0, const float* __restrict__ an1, const float* __restrict__ an2,
    const float* __restrict__ an3, const float* __restrict__ an4,
    const float* __restrict__ c3, const float* __restrict__ c4, const float* __restrict__ c5,
    const float* __restrict__ c6, const float* __restrict__ c7,
    const float* __restrict__ img, float* __restrict__ boxes,
    u64* __restrict__ listT_g, u32* __restrict__ cnt_pad)
{
  int blk = blockIdx.x, tid = threadIdx.x;
  if (blk < 600) {
    // ---- decode + clip ----
    int t = blk * 256 + tid;
    if (t >= 2 * A_TOTAL) return;
    int b = t / A_TOTAL, a = t % A_TOTAL;
    const float* bp; const float* ap; int al; int nl;
    if (a < 57600)      { bp = bx0; ap = an0; al = a;          nl = 57600; }
    else if (a < 72000) { bp = bx1; ap = an1; al = a - 57600;  nl = 14400; }
    else if (a < 75600) { bp = bx2; ap = an2; al = a - 72000;  nl = 3600;  }
    else if (a < 76500) { bp = bx3; ap = an3; al = a - 75600;  nl = 900;   }
    else                { bp = bx4; ap = an4; al = a - 76500;  nl = 225;   }
    float4 e  = *(const float4*)(bp + ((size_t)b * nl + al) * 4);
    float4 an = *(const float4*)(ap + ((size_t)b * nl + al) * 4);
    const float CLIP = 4.135166556742356f; // log(1000/16)
    float ah  = an.z - an.x + 1.0f;
    float aw  = an.w - an.y + 1.0f;
    float ayc = an.x + 0.5f * ah;
    float axc = an.y + 0.5f * aw;
    float dh = fminf(e.z, CLIP), dw = fminf(e.w, CLIP);
    float yc = e.x * ah + ayc;
    float xc = e.y * aw + axc;
    float h  = expf(dh) * ah;
    float w  = expf(dw) * aw;
    float ymin = yc - 0.5f * h;
    float xmin = xc - 0.5f * w;
    float ymax = ymin + h - 1.0f;
    float xmax = xmin + w - 1.0f;
    float H = img[b * 2 + 0], W = img[b * 2 + 1];
    float4 o;
    o.x = fminf(fmaxf(ymin, 0.0f), H);
    o.y = fminf(fmaxf(xmin, 0.0f), W);
    o.z = fminf(fmaxf(ymax, 0.0f), H);
    o.w = fminf(fmaxf(xmax, 0.0f), W);
    *(float4*)(boxes + (size_t)t * 4) = o;
    return;
  }
  // ---- streaming collect (slice = blk2 & 7 decorrelates counter contention) ----
  int blk2 = blk - 600;
  int slice = blk2 & 7;
  const float* cls; int n, base, b, loc, J, lvl;
  if (blk2 < 2560)      { lvl = 0; cls = c3; n = 57600; base = 0;     J = 1280; int r = blk2;        b = r >= J; loc = b ? r - J : r; }
  else if (blk2 < 3200) { lvl = 1; cls = c4; n = 14400; base = 57600; J = 320;  int r = blk2 - 2560; b = r >= J; loc = b ? r - J : r; }
  else if (blk2 < 3360) { lvl = 2; cls = c5; n = 3600;  base = 72000; J = 80;   int r = blk2 - 3200; b = r >= J; loc = b ? r - J : r; }
  else if (blk2 < 3400) { lvl = 3; cls = c6; n = 900;   base = 75600; J = 20;   int r = blk2 - 3360; b = r >= J; loc = b ? r - J : r; }
  else                  { lvl = 4; cls = c7; n = 225;   base = 76500; J = 10;   int r = blk2 - 3400; b = r >= J; loc = b ? r - J : r; }

  if (lvl <= 3) {
    int F4 = n * 91 / 4;
    int chunk = (F4 + J - 1) / J;
    int q0 = loc * chunk;
    int q1 = q0 + chunk; if (q1 > F4) q1 = F4;
    const float4* src4 = (const float4*)(cls + (size_t)b * n * 91);
    for (int q = q0 + tid; q < q1; q += 256) {
      float4 v = src4[q];
      int i0 = q << 2;
      coll_elem(i0,     v.x, b, base, slice, listT_g, cnt_pad);
      coll_elem(i0 + 1, v.y, b, base, slice, listT_g, cnt_pad);
      coll_elem(i0 + 2, v.z, b, base, slice, listT_g, cnt_pad);
      coll_elem(i0 + 3, v.w, b, base, slice, listT_g, cnt_pad);
    }
  } else {
    int F = n * 91;                 // 20475 (not /4-divisible) -> scalar
    int chunk = (F + J - 1) / J;
    int s0 = loc * chunk;
    int s1 = s0 + chunk; if (s1 > F) s1 = F;
    const float* src = cls + (size_t)b * F;
    for (int i = s0 + tid; i < s1; i += 256) coll_elem(i, src[i], b, base, slice, listT_g, cnt_pad);
  }
}

// ---------------- per-lane NMS: rank-select fast path + full-sort mid path + exact fallback ----------------
__global__ __launch_bounds__(256) void nms_kernel(
    const float* __restrict__ c3, const float* __restrict__ c4, const float* __restrict__ c5,
    const float* __restrict__ c6, const float* __restrict__ c7,
    const float* __restrict__ boxes, const u64* __restrict__ listT_g,
    const u32* __restrict__ cnt_pad, float* __restrict__ nms_s, float* __restrict__ nms_b)
{
  __shared__ __align__(16) char big[40960];     // fallback: listA u64[5120] -> cntArr u32[4096]
  __shared__ __align__(16) u64 listE[2048];     // fallback only
  __shared__ u64 key_s[2048];
  __shared__ __align__(16) u32 histL[4096];     // hist; fast path reuses as sel u64[768]
  __shared__ float4 wbox[MAXT];
  __shared__ u32 wtot[4];
  __shared__ u32 sh_flag, sh_mid, sh_bigS, sh_cS;
  __shared__ u64 sh_minPrev;
  __shared__ u32 sh_w, sh_done, sh_eidx, sh_Rthr, sh_eSorted, sh_bigF;
  __shared__ u32 sh_B, sh_incl, sh_above, sh_total, sh_cA, sh_cE, sh_B2;

  int tid = threadIdx.x;
  int lane = blockIdx.x;
  int b = lane / NCLS, c = lane % NCLS;
  const float4* boxes4 = (const float4*)boxes;
  size_t bbase = (size_t)b * A_TOTAL;
  const u64 thrpack = ((u64)KTHR) << 32;

  float* outS = nms_s + (size_t)lane * MAXT;
  float* outB = nms_b + (size_t)lane * MAXT * 4;

  // ---- read sliced counters, build prefix ----
  u32 pre[9]; pre[0] = 0;
  bool of = false;
  #pragma unroll
  for (int j = 0; j < 8; ++j) {
    u32 cj = cnt_pad[lane * 128 + j * 16];
    of |= (cj > SCAP);
    pre[j + 1] = pre[j] + cj;
  }
  u32 cnt = pre[8];
  if (tid == 0) { sh_flag = (of || cnt > TCAP) ? 1u : 0u; sh_mid = 0; sh_bigS = 0; }
  __syncthreads();

  if (!sh_flag) {
    // ---- load this lane's keys into registers (8/thread) from the 8 slice segments ----
    u64 kr[8];
    #pragma unroll
    for (int r = 0; r < 8; ++r) {
      u32 s = (u32)tid + (u32)r * 256u;
      u64 k = 0ull;
      if (s < cnt) {
        u32 j = 0;
        #pragma unroll
        for (int t = 1; t < 8; ++t) if (s >= pre[t]) j = (u32)t;
        k = listT_g[(((size_t)lane * 8 + j) << 9) + (s - pre[j])];
      }
      kr[r] = k;
    }

    // ========== FAST: sorted top-NSEL prefix ==========
    for (int i = tid; i < 4096; i += 256) histL[i] = 0;
    __syncthreads();
    #pragma unroll
    for (int r = 0; r < 8; ++r) if (kr[r]) atomicAdd(&histL[dig05(kr[r])], 1u);
    __syncthreads();
    if (tid < 64) {
      u32 Bx, ix, ax, tx;
      cut4096w(histL, NSEL, tid, Bx, ix, ax, tx);
      if (tid == 0) { sh_B = Bx; sh_incl = ix; sh_total = tx; sh_cS = 0; }
    }
    __syncthreads();
    u32 B = sh_B, incl = sh_incl, total = sh_total;
    bool selAll = (total < NSEL);
    u32 Csel = selAll ? total : incl;
    if (Csel <= 768u) {
      u64* sel = (u64*)histL;     // reuse (cut reads complete; barrier above)
      #pragma unroll
      for (int r = 0; r < 8; ++r) {
        u64 k = kr[r];
        if (k && (selAll || (u32)dig05(k) >= B)) {
          u32 p = atomicAdd(&sh_cS, 1u);
          if (p < 768u) sel[p] = k;
        }
      }
      __syncthreads();
      u32 Cs = sh_cS; if (Cs > 768u) Cs = 768u;
      // rank-by-comparison -> exact descending order (keys unique)
      for (u32 j = tid; j < Cs; j += 256) {
        u64 kj = sel[j];
        u32 rk = 0;
        for (u32 i2 = 0; i2 < Cs; ++i2) rk += (sel[i2] > kj) ? 1u : 0u;
        key_s[rk] = kj;
      }
      __syncthreads();
      if (tid < 64) {
        int w = lazy_scan_g(key_s, boxes4, bbase, (int)Cs, wbox, outS, outB, 0, tid);
        if (tid == 0) {
          sh_w = (u32)w;
          // 100 winners inside the sorted prefix are provably the global first 100.
          if (w < MAXT) { if (selAll) sh_flag = 1; else sh_mid = 1; }
        }
      }
    } else {
      if (tid == 0) sh_mid = 1;
    }
    __syncthreads();

    // ========== MID: counting-sort ALL s>=0.5 candidates, rescan ==========
    if (sh_mid && !sh_flag) {
      for (int i = tid; i < 4096; i += 256) histL[i] = 0;
      if (tid == 0) sh_bigS = 0;
      __syncthreads();
      #pragma unroll
      for (int r = 0; r < 8; ++r) if (kr[r]) atomicAdd(&histL[dig05(kr[r])], 1u);
      __syncthreads();
      // descending exclusive prefix
      {
        int t0 = tid << 4;
        u32 hloc[16]; u32 ssum = 0;
        #pragma unroll
        for (int j = 0; j < 16; ++j) { hloc[j] = histL[t0 + j]; ssum += hloc[j]; }
        int wl = tid & 63, wid = tid >> 6;
        u32 suf = ssum;
        #pragma unroll
        for (int off = 1; off < 64; off <<= 1) {
          u32 v = __shfl_down(suf, off, 64);
          if (wl < 64 - off) suf += v;
        }
        if (wl == 0) wtot[wid] = suf;
        __syncthreads();
        u32 cross = 0;
        for (int w2 = wid + 1; w2 < 4; ++w2) cross += wtot[w2];
        u32 run = (suf - ssum) + cross;
        #pragma unroll
        for (int j = 15; j >= 0; --j) { u32 b2 = run; run += hloc[j]; histL[t0 + j] = b2; }
      }
      __syncthreads();
      #pragma unroll
      for (int r = 0; r < 8; ++r) {
        u64 k = kr[r];
        if (k) {
          u32 pos = atomicAdd(&histL[dig05(k)], 1u);
          if (pos < TCAP) key_s[pos] = k;
        }
      }
      __syncthreads();
      // per-bucket insertion minisort; bucket d spans [histL[d+1], histL[d])
      {
        int t0 = tid << 4;
        for (int j = 0; j < 16; ++j) {
          u32 d = (u32)(t0 + j);
          u32 end = histL[d];
          u32 start = (d == 4095u) ? 0u : histL[d + 1];
          u32 cc = end - start;
          if (cc >= 2u) {
            if (cc <= 48u) {
              for (u32 a2 = start + 1; a2 < end; ++a2) {
                u64 kv = key_s[a2];
                int bi = (int)a2 - 1;
                while (bi >= (int)start && key_s[bi] < kv) { key_s[bi + 1] = key_s[bi]; --bi; }
                key_s[bi + 1] = kv;
              }
            } else sh_bigS = 1;
          }
        }
      }
      __syncthreads();
      if (sh_bigS) bitonic_desc(key_s, cnt, tid, 256);
      if (tid < 64) {
        int w = lazy_scan_g(key_s, boxes4, bbase, (int)cnt, wbox, outS, outB, 0, tid);
        if (tid == 0) {
          sh_w = (u32)w;
          if (w < MAXT) sh_flag = 1;   // s>=0.5 pool exhausted -> exact needed
        }
      }
    }
  }
  __syncthreads();
  if (!sh_flag) {
    u32 w = sh_w;
    for (u32 p = w + (u32)tid; p < MAXT; p += 256) {
      outS[p] = -1.0f;
      *(float4*)(outB + p * 4) = make_float4(0.f, 0.f, 0.f, 0.f);
    }
    return;
  }

  // ================= EXACT FALLBACK (rare): rebuild from raw column =================
  auto sb_of = [&](int i) -> u32 {
    const float* p; int al, nl;
    if (i < 57600)      { p = c3; al = i;          nl = 57600; }
    else if (i < 72000) { p = c4; al = i - 57600;  nl = 14400; }
    else if (i < 75600) { p = c5; al = i - 72000;  nl = 3600;  }
    else if (i < 76500) { p = c6; al = i - 75600;  nl = 900;   }
    else                { p = c7; al = i - 76500;  nl = 225;   }
    float x = p[((size_t)b * nl + al) * 91 + (c + 1)];
    float s = 1.0f / (1.0f + expf(-x));
    return __float_as_uint(s);
  };

  u64* listA = (u64*)big;
  for (int i = tid; i < 4096; i += 256) histL[i] = 0;
  if (tid == 0) {
    sh_cA = 0; sh_cE = 0; sh_w = 0; sh_done = 0; sh_eidx = 0; sh_eSorted = 0; sh_minPrev = ~0ull;
  }
  __syncthreads();
  for (int i = tid; i < A_TOTAL; i += 256) atomicAdd(&histL[sb_of(i) >> 19], 1u);
  __syncthreads();
  if (tid < 64) {
    u32 Bx, ix, ax, tx;
    cut4096w(histL, KTOP, tid, Bx, ix, ax, tx);
    if (tid == 0) sh_B = Bx;
  }
  __syncthreads();
  u32 B = sh_B;
  for (int i = tid; i < A_TOTAL; i += 256) {
    u32 u = sb_of(i);
    u32 bkt = u >> 19;
    if (bkt > B) {
      u32 p = atomicAdd(&sh_cA, 1u);
      if (p < 5120u) listA[p] = pack_key(u, (u32)i);
    } else if (bkt == B) {
      u32 p = atomicAdd(&sh_cE, 1u);
      if (p < 2048u) listE[p] = pack_key(u, (u32)i);
    }
  }
  __syncthreads();
  u32 g = sh_cA, h = sh_cE;
  if (h > 2048u) {
    for (int i = tid; i < 4096; i += 256) histL[i] = 0;
    if (tid == 0) sh_cE = 0;
    __syncthreads();
    for (int i = tid; i < A_TOTAL; i += 256) {
      u32 u = sb_of(i);
      if ((u >> 19) == B) atomicAdd(&histL[(u >> 7) & 0xFFFu], 1u);
    }
    __syncthreads();
    u32 R1 = KTOP - g;
    if (tid < 64) {
      u32 Bx, ix, ax, tx;
      cut4096w(histL, R1, tid, Bx, ix, ax, tx);
      if (tid == 0) sh_B2 = Bx;
    }
    __syncthreads();
    u32 B2 = sh_B2;
    for (int i = tid; i < A_TOTAL; i += 256) {
      u32 u = sb_of(i);
      if ((u >> 19) == B) {
        u32 sb2 = (u >> 7) & 0xFFFu;
        if (sb2 > B2) {
          u32 p = atomicAdd(&sh_cA, 1u);
          if (p < 5120u) listA[p] = pack_key(u, (u32)i);
        } else if (sb2 == B2) {
          u32 p = atomicAdd(&sh_cE, 1u);
          if (p < 2048u) listE[p] = pack_key(u, (u32)i);
        }
      }
    }
    __syncthreads();
    g = sh_cA; h = sh_cE; if (h > 2048u) h = 2048u;
  }
  if (g > 5120u) g = 5120u;
  u32 R = (g < KTOP) ? (KTOP - g) : 0u; if (R > h) R = h;

  u64 ak[20];
  #pragma unroll
  for (int r = 0; r < 20; ++r) {
    u32 s2 = (u32)tid + (u32)r * 256u;
    u64 kp = (s2 < g) ? listA[s2] : 0ull;
    if (kp < thrpack) kp = 0ull;
    ak[r] = kp;
  }
  __syncthreads();
  u32* cntArr = (u32*)big;

  const float LO0  = 0.04f;
  const float INV0 = 4096.0f / (1.001f - 0.04f);

  for (int seg = 0; seg < 7200; ++seg) {
    __syncthreads();
    if (sh_w >= MAXT || sh_done) break;
    u64 minPrev = sh_minPrev;

    int digLvl = 0;
    u32 A_B0 = 0, A_B1 = 0;
    float lo1 = 0.f, inv1 = 0.f;
    u64 kMask = 0, kPref = 0;
    int m1shift = 32;
    int selMode = -1;
    u32 selB = 0;
    u32 C = 0;
    bool fromE = false;

    for (int lvl = 0; lvl < 8; ++lvl) {
      for (int i = tid; i < 4096; i += 256) histL[i] = 0;
      __syncthreads();
      #pragma unroll
      for (int r = 0; r < 20; ++r) {
        u64 k = ak[r];
        if (!k || k >= minPrev) continue;
        float s = __uint_as_float((u32)(k >> 32));
        if (digLvl >= 1) { int d0 = (int)((s - LO0) * INV0); d0 = min(max(d0, 0), 4095); if ((u32)d0 != A_B0) continue; }
        if (digLvl >= 2) { int d1 = (int)((s - lo1) * inv1); d1 = min(max(d1, 0), 4095); if ((u32)d1 != A_B1) continue; }
        if (digLvl >= 3 && ((k & kMask) != kPref)) continue;
        u32 d;
        if (digLvl == 0)      { int t0 = (int)((s - LO0) * INV0); d = (u32)min(max(t0, 0), 4095); }
        else if (digLvl == 1) { int t1 = (int)((s - lo1) * inv1); d = (u32)min(max(t1, 0), 4095); }
        else                  d = (u32)((k >> m1shift) & 0xFFFull);
        atomicAdd(&histL[d], 1u);
      }
      __syncthreads();
      if (tid < 64) {
        u32 Bx, ix, ax, tx;
        cut4096w(histL, 1024u, tid, Bx, ix, ax, tx);
        if (tid == 0) { sh_B = Bx; sh_incl = ix; sh_above = ax; sh_total = tx; }
      }
      __syncthreads();
      u32 total = sh_total, incl = sh_incl, above = sh_above, Bx = sh_B;
      if (total == 0u)   { fromE = true; break; }
      if (total < 1024u) { selMode = 0; C = total; break; }
      if (incl <= 2048u) { selMode = 1; selB = Bx; C = incl; break; }
      if (above > 0u)    { selMode = 2; selB = Bx; C = above; break; }
      if (digLvl == 0) {
        A_B0 = Bx;
        lo1 = LO0 + (float)Bx / INV0;
        inv1 = INV0 * 4096.0f;
        digLvl = 1;
      } else if (digLvl == 1) {
        A_B1 = Bx;
        digLvl = 2; m1shift = 32;
      } else {
        kPref |= ((u64)Bx << m1shift);
        kMask |= (0xFFFull << m1shift);
        m1shift -= 12;
        digLvl++;
      }
      __syncthreads();
    }

    if (fromE) {
      if (!sh_eSorted) {
        bitonic_desc(listE, h, tid, 256);
        if (tid == 0) {
          u32 lo = 0, hi2 = h;
          while (lo < hi2) { u32 mid = (lo + hi2) >> 1; if (listE[mid] >= thrpack) lo = mid + 1; else hi2 = mid; }
          sh_Rthr = (R < lo) ? R : lo;
          sh_eSorted = 1;
        }
        __syncthreads();
      }
      u32 eidx = sh_eidx;
      u32 take = (sh_Rthr > eidx) ? (sh_Rthr - eidx) : 0u;
      if (take > 2048u) take = 2048u;
      if (take == 0u) { if (tid == 0) sh_done = 1; continue; }
      for (u32 i = tid; i < take; i += 256) key_s[i] = listE[eidx + i];
      C = take;
      if (tid == 0) sh_eidx = eidx + take;
    } else {
      u32 hloc[16];
      {
        int t0 = tid << 4;
        u32 ssum = 0;
        #pragma unroll
        for (int j = 0; j < 16; ++j) { hloc[j] = histL[t0 + j]; ssum += hloc[j]; }
        int wl = tid & 63, wid = tid >> 6;
        u32 suf = ssum;
        #pragma unroll
        for (int off = 1; off < 64; off <<= 1) {
          u32 v = __shfl_down(suf, off, 64);
          if (wl < 64 - off) suf += v;
        }
        if (wl == 0) wtot[wid] = suf;
        __syncthreads();
        u32 cross = 0;
        for (int w2 = wid + 1; w2 < 4; ++w2) cross += wtot[w2];
        u32 run = (suf - ssum) + cross;
        #pragma unroll
        for (int j = 15; j >= 0; --j) { u32 base2 = run; run += hloc[j]; histL[t0 + j] = base2; }
      }
      for (int i = tid; i < 4096; i += 256) cntArr[i] = 0;
      if (tid == 0) sh_bigF = 0;
      __syncthreads();
      #pragma unroll
      for (int r = 0; r < 20; ++r) {
        u64 k = ak[r];
        if (!k || k >= minPrev) continue;
        float s = __uint_as_float((u32)(k >> 32));
        if (digLvl >= 1) { int d0 = (int)((s - LO0) * INV0); d0 = min(max(d0, 0), 4095); if ((u32)d0 != A_B0) continue; }
        if (digLvl >= 2) { int d1 = (int)((s - lo1) * inv1); d1 = min(max(d1, 0), 4095); if ((u32)d1 != A_B1) continue; }
        if (digLvl >= 3 && ((k & kMask) != kPref)) continue;
        u32 d;
        if (digLvl == 0)      { int t0x = (int)((s - LO0) * INV0); d = (u32)min(max(t0x, 0), 4095); }
        else if (digLvl == 1) { int t1x = (int)((s - lo1) * inv1); d = (u32)min(max(t1x, 0), 4095); }
        else                  d = (u32)((k >> m1shift) & 0xFFFull);
        if (selMode == 1)      { if (d < selB) continue; }
        else if (selMode == 2) { if (d <= selB) continue; }
        u32 pos = histL[d] + atomicAdd(&cntArr[d], 1u);
        if (pos < 2048u) key_s[pos] = k;
      }
      __syncthreads();
      {
        int t0 = tid << 4;
        for (int j = 0; j < 16; ++j) {
          u32 bkt = (u32)(t0 + j);
          u32 cc = cntArr[bkt];
          if (cc >= 2u) {
            if (cc <= 48u) {
              u32 basep = histL[bkt];
              for (u32 a2 = 1; a2 < cc; ++a2) {
                u64 kv = key_s[basep + a2];
                int bi = (int)a2 - 1;
                while (bi >= 0 && key_s[basep + bi] < kv) { key_s[basep + bi + 1] = key_s[basep + bi]; --bi; }
                key_s[basep + bi + 1] = kv;
              }
            } else sh_bigF = 1;
          }
        }
      }
      __syncthreads();
      if (sh_bigF) bitonic_desc(key_s, C, tid, 256);
      if (tid == 0) sh_minPrev = key_s[C - 1];
    }
    __syncthreads();

    if (tid < 64) {
      int w = lazy_scan_g(key_s, boxes4, bbase, (int)C, wbox, outS, outB, (int)sh_w, tid);
      if (tid == 0) sh_w = (u32)w;
    }
  }

  __syncthreads();
  u32 w = sh_w;
  for (u32 p = w + (u32)tid; p < MAXT; p += 256) {
    outS[p] = -1.0f;
    *(float4*)(outB + p * 4) = make_float4(0.f, 0.f, 0.f, 0.f);
  }
}

// ---------------- final per-batch top-100: radix rank-select ----------------
__global__ __launch_bounds__(256) void merge_kernel(
    const float* __restrict__ nms_s, const float* __restrict__ nms_b,
    float* __restrict__ out_b, float* __restrict__ out_s,
    float* __restrict__ out_c, float* __restrict__ out_v)
{
  __shared__ u64 keys[NCLS * MAXT];   // 72 KB
  __shared__ u32 hist[4096];          // 16 KB
  __shared__ u64 sel[640];
  __shared__ u32 sh_cnt, sh_valid;
  __shared__ u32 sh_B, sh_incl, sh_above, sh_total;

  int b = blockIdx.x, tid = threadIdx.x;
  const int NTOT = NCLS * MAXT;

  for (int i = tid; i < NTOT; i += 256) {
    float s = nms_s[(size_t)b * NTOT + i];
    u32 u = __float_as_uint(s);
    u = (u & 0x80000000u) ? ~u : (u | 0x80000000u);
    keys[i] = ((u64)u << 32) | (u64)(0xFFFFFFFFu - (u32)i);
  }
  if (tid == 0) { sh_cnt = 0; sh_valid = 0; }

  u64 prefVal = 0;
  u64 T = 0;
  u32 need = MAXT;
  const int shifts[6] = {52, 40, 28, 16, 4, 0};
  const int widths[6] = {12, 12, 12, 12, 12, 4};
  for (int lvl = 0; lvl < 6; ++lvl) {
    int s = shifts[lvl], w = widths[lvl];
    for (int i = tid; i < 4096; i += 256) hist[i] = 0;
    __syncthreads();
    u32 dmask = (1u << w) - 1u;
    for (int i = tid; i < NTOT; i += 256) {
      u64 k = keys[i];
      if (lvl > 0 && (k >> (s + w)) != (prefVal >> (s + w))) continue;
      atomicAdd(&hist[(u32)((k >> s) & dmask)], 1u);
    }
    __syncthreads();
    if (tid < 64) {
      u32 Bx, ix, ax, tx;
      cut4096w(hist, need, tid, Bx, ix, ax, tx);
      if (tid == 0) { sh_B = Bx; sh_incl = ix; sh_above = ax; sh_total = tx; }
    }
    __syncthreads();
    u32 B = sh_B, incl = sh_incl, above = sh_above;
    if (incl <= 512u || lvl == 5) {
      T = prefVal | ((u64)B << s);
      break;
    }
    prefVal |= ((u64)B << s);
    need -= above;
  }
  __syncthreads();

  for (int i = tid; i < NTOT; i += 256) {
    u64 k = keys[i];
    if (k >= T) {
      u32 p = atomicAdd(&sh_cnt, 1u);
      if (p < 640u) sel[p] = k;
    }
  }
  __syncthreads();
  u32 cnt = sh_cnt; if (cnt > 640u) cnt = 640u;

  for (u32 j = tid; j < cnt; j += 256) {
    u64 kj = sel[j];
    u32 r = 0;
    for (u32 i = 0; i < cnt; ++i) r += (sel[i] > kj) ? 1u : 0u;
    if (r < (u32)MAXT) {
      u32 u = (u32)(kj >> 32);
      u32 bits = (u & 0x80000000u) ? (u ^ 0x80000000u) : ~u;
      float sc = __uint_as_float(bits);
      u32 flat = 0xFFFFFFFFu - (u32)(kj & 0xFFFFFFFFull);
      int cls = (int)(flat / MAXT), pos = (int)(flat % MAXT);
      out_s[b * MAXT + r] = sc;
      out_c[b * MAXT + r] = (float)(cls + 1);
      *(float4*)(out_b + ((size_t)b * MAXT + r) * 4) =
          *(const float4*)(nms_b + (((size_t)b * NCLS + cls) * MAXT + pos) * 4);
      if (sc > -1.0f) atomicAdd(&sh_valid, 1u);
    }
  }
  __syncthreads();
  if (tid == 0) out_v[b] = (float)sh_valid;
}

extern "C" void kernel_launch(void* const* d_in, const int* in_sizes, int n_in,
                              void* d_out, int out_size, void* d_ws, size_t ws_size,
                              hipStream_t stream)
{
  const float* box[5]; const float* cls[5]; const float* anc[5];
  bool interleaved = (in_sizes[1] == 2 * 57600 * 91);   // setup_inputs dict order
  if (interleaved) {
    for (int l = 0; l < 5; ++l) {
      box[l] = (const float*)d_in[3 * l + 0];
      cls[l] = (const float*)d_in[3 * l + 1];
      anc[l] = (const float*)d_in[3 * l + 2];
    }
  } else {
    for (int l = 0; l < 5; ++l) {
      box[l] = (const float*)d_in[l];
      cls[l] = (const float*)d_in[5 + l];
      anc[l] = (const float*)d_in[10 + l];
    }
  }
  const float* img = (const float*)d_in[15];

  float* ws = (float*)d_ws;
  float* boxes_ws = ws;                              // 613800 f
  u32*   cnt_pad  = (u32*)(boxes_ws + 613800);       // 180*128 u32 (8 slices x 64B stride)
  u64*   listT_g  = (u64*)(cnt_pad + 180 * 128);     // 180*8*512 u64
  float* nms_s    = (float*)(listT_g + 180 * 8 * 512); // 18000 f
  float* nms_b    = nms_s + 18000;                   // 72000 f

  hipMemsetAsync(cnt_pad, 0, 180 * 128 * sizeof(u32), stream);

  front_kernel<<<4020, 256, 0, stream>>>(
      box[0], box[1], box[2], box[3], box[4],
      anc[0], anc[1], anc[2], anc[3], anc[4],
      cls[0], cls[1], cls[2], cls[3], cls[4],
      img, boxes_ws, listT_g, cnt_pad);

  nms_kernel<<<180, 256, 0, stream>>>(cls[0], cls[1], cls[2], cls[3], cls[4],
                                      boxes_ws, listT_g, cnt_pad, nms_s, nms_b);

  float* out_b = (float*)d_out;  // [2][100][4]
  float* out_s = out_b + 800;    // [2][100]
  float* out_c = out_s + 200;    // [2][100]
  float* out_v = out_c + 200;    // [2]
  merge_kernel<<<2, 256, 0, stream>>>(nms_s, nms_b, out_b, out_s, out_c, out_v);
}